// Round 10
// baseline (704.298 us; speedup 1.0000x reference)
//
#include <hip/hip_runtime.h>
#include <hip/hip_bf16.h>
#include <math.h>

#define N_ATOMS 8192
#define N_EDGES 262144
#define N_MOL   128
#define FDIM    128
#define RDIM    20
#define LLAYERS 3
#define CUTOFF  5.0f
#define EPSV    1e-8f
#define PI_F    3.14159265358979323846f

typedef __attribute__((ext_vector_type(8))) short bf16x8;
typedef __attribute__((ext_vector_type(4))) float f32x4;

#define VPLANE 1048576   // 8192*128 elements per component plane

__device__ __forceinline__ ushort f2bf(float x) {
    uint b = __float_as_uint(x);
    return (ushort)((b + 0x7fffu + ((b >> 16) & 1u)) >> 16);
}

// ---------------- weight convert+transpose (f32 KxN -> bf16 NxK) ----------------
__global__ void k_wconv(const float* __restrict__ w1, const float* __restrict__ w2,
                        const float* __restrict__ uu, const float* __restrict__ uvw,
                        const float* __restrict__ a1, const float* __restrict__ a2,
                        const float* __restrict__ ow1, ushort* __restrict__ WT) {
    int i = blockIdx.x * 256 + threadIdx.x;  // < 557056
    float v;
    if (i < 49152) {                          // W1T
        int idx = i; int l = idx >> 14; idx &= 16383;
        int n = idx >> 7, k = idx & 127;
        v = w1[l*16384 + k*128 + n];
    } else if (i < 196608) {                  // W2T
        int idx = i - 49152; int l = idx / 49152; idx -= l * 49152;
        int n = idx >> 7, k = idx & 127;
        v = w2[l*49152 + k*384 + n];
    } else if (i < 294912) {                  // UVT (u cols 0-127, v cols 128-255)
        int idx = i - 196608; int l = idx >> 15; idx &= 32767;
        int n = idx >> 7, k = idx & 127;
        v = (n < 128) ? uu[l*16384 + k*128 + n] : uvw[l*16384 + k*128 + (n-128)];
    } else if (i < 393216) {                  // A1T (128n x 256k)
        int idx = i - 294912; int l = idx >> 15; idx &= 32767;
        int n = idx >> 8, k = idx & 255;
        v = a1[l*32768 + k*128 + n];
    } else if (i < 540672) {                  // A2T
        int idx = i - 393216; int l = idx / 49152; idx -= l * 49152;
        int n = idx >> 7, k = idx & 127;
        v = a2[l*49152 + k*384 + n];
    } else {                                  // OW1T
        int idx = i - 540672;
        int n = idx >> 7, k = idx & 127;
        v = ow1[k*128 + n];
    }
    WT[i] = f2bf(v);
}

// ---------------- embed gather ----------------
__global__ void k_embed(const int* __restrict__ z, const float* __restrict__ embed,
                        float* __restrict__ S, ushort* __restrict__ SBF) {
    int i = blockIdx.x * 256 + threadIdx.x;
    int a = i >> 7, k = i & 127;
    float v = embed[(size_t)z[a] * FDIM + k];
    S[i] = v; SBF[i] = f2bf(v);
}

// ---------------- CSR build ----------------
__global__ void k_hist(const int* __restrict__ edst, int* __restrict__ CNT) {
    int e = blockIdx.x * 256 + threadIdx.x;
    if (e < N_EDGES) atomicAdd(&CNT[edst[e]], 1);
}

__global__ __launch_bounds__(1024) void k_scan(const int* __restrict__ CNT,
                                               int* __restrict__ OFF, int* __restrict__ CUR) {
    __shared__ int part[1024];
    int t = threadIdx.x;
    int loc[8];
    int run = 0;
    #pragma unroll
    for (int i = 0; i < 8; i++) { int c = CNT[t*8 + i]; loc[i] = run; run += c; }
    part[t] = run;
    __syncthreads();
    for (int off = 1; off < 1024; off <<= 1) {
        int v = 0;
        if (t >= off) v = part[t - off];
        __syncthreads();
        part[t] += v;
        __syncthreads();
    }
    int ebase = (t > 0) ? part[t-1] : 0;
    #pragma unroll
    for (int i = 0; i < 8; i++) { int o = ebase + loc[i]; OFF[t*8+i] = o; CUR[t*8+i] = o; }
    if (t == 1023) OFF[8192] = part[1023];
}

// ---------------- edge geometry + rbf, CSR-sorted (k_pos fused: atomicAdd -> slot) ----------------
__global__ void k_edges(const float* __restrict__ pos, const int* __restrict__ esrc,
                        const int* __restrict__ edst, int* __restrict__ CUR,
                        float* __restrict__ RBF, float* __restrict__ UNITFC,
                        int* __restrict__ SRCS) {
    int e = blockIdx.x * 256 + threadIdx.x;
    if (e >= N_EDGES) return;
    int s = esrc[e], d = edst[e];
    int p = atomicAdd(&CUR[d], 1);
    float rx = pos[d*3+0] - pos[s*3+0];
    float ry = pos[d*3+1] - pos[s*3+1];
    float rz = pos[d*3+2] - pos[s*3+2];
    float dd = sqrtf(rx*rx + ry*ry + rz*rz + EPSV);
    float inv = 1.0f / dd;
    float fc = (dd < CUTOFF) ? 0.5f * (cosf(dd * (PI_F / CUTOFF)) + 1.0f) : 0.0f;
    float4 u4; u4.x = rx*inv; u4.y = ry*inv; u4.z = rz*inv; u4.w = fc;
    *(float4*)&UNITFC[(size_t)p*4] = u4;
    SRCS[p] = s;
    float rb[RDIM];
    #pragma unroll
    for (int r = 0; r < RDIM; r++) {
        float freq = (float)(r + 1) * (PI_F / CUTOFF);
        rb[r] = sinf(dd * freq) * inv;
    }
    float4* out = (float4*)&RBF[(size_t)p * RDIM];
    #pragma unroll
    for (int q = 0; q < 5; q++) {
        float4 o; o.x = rb[q*4]; o.y = rb[q*4+1]; o.z = rb[q*4+2]; o.w = rb[q*4+3];
        out[q] = o;
    }
}

// ---------------- fused message MLP (4 waves): PHIB = (silu(S@w1+b1))@w2+b2 ----------------
__global__ __launch_bounds__(256) void k_msg(
    const ushort* __restrict__ SBF, const ushort* __restrict__ W1T, const float* __restrict__ b1,
    const ushort* __restrict__ W2T, const float* __restrict__ b2, ushort* __restrict__ PHIB)
{
    int tid = threadIdx.x;
    int w = tid >> 6, l = tid & 63;
    int bm = blockIdx.x * 16;
    int lrow = l & 15, lk = (l >> 4) * 8;
    __shared__ ushort Hs[16][136];

    f32x4 acc[2] = {{0.f,0.f,0.f,0.f},{0.f,0.f,0.f,0.f}};
    #pragma unroll
    for (int k0 = 0; k0 < 128; k0 += 32) {
        bf16x8 af = *(const bf16x8*)&SBF[(size_t)(bm + lrow)*128 + k0 + lk];
        #pragma unroll
        for (int t = 0; t < 2; t++) {
            int n = (2*w + t)*16 + lrow;
            bf16x8 bf = *(const bf16x8*)&W1T[(size_t)n*128 + k0 + lk];
            acc[t] = __builtin_amdgcn_mfma_f32_16x16x32_bf16(af, bf, acc[t], 0, 0, 0);
        }
    }
    #pragma unroll
    for (int t = 0; t < 2; t++) {
        int col = (2*w + t)*16 + lrow;
        float bv = b1[col];
        #pragma unroll
        for (int j = 0; j < 4; j++) {
            int row = (l >> 4)*4 + j;
            float val = acc[t][j] + bv;
            val = val / (1.0f + __expf(-val));
            Hs[row][col] = f2bf(val);
        }
    }
    __syncthreads();

    f32x4 acc2[6];
    #pragma unroll
    for (int t = 0; t < 6; t++) acc2[t] = (f32x4){0.f,0.f,0.f,0.f};
    #pragma unroll
    for (int k0 = 0; k0 < 128; k0 += 32) {
        bf16x8 af = *(const bf16x8*)&Hs[lrow][k0 + lk];
        #pragma unroll
        for (int t = 0; t < 6; t++) {
            int n = (6*w + t)*16 + lrow;
            bf16x8 bf = *(const bf16x8*)&W2T[(size_t)n*128 + k0 + lk];
            acc2[t] = __builtin_amdgcn_mfma_f32_16x16x32_bf16(af, bf, acc2[t], 0, 0, 0);
        }
    }
    #pragma unroll
    for (int t = 0; t < 6; t++) {
        int col = (6*w + t)*16 + lrow;
        float bv = b2[col];
        #pragma unroll
        for (int j = 0; j < 4; j++) {
            int row = bm + (l >> 4)*4 + j;
            PHIB[(size_t)row*384 + col] = f2bf(acc2[t][j] + bv);
        }
    }
}

// ---------------- edge aggregation: depth-3 copy-free gather pipeline ----------------
__global__ __launch_bounds__(192) void k_aggregate(
    const ushort* __restrict__ PHIB, const ushort* __restrict__ VBFA,
    float* __restrict__ S, ushort* __restrict__ SBF,
    float* __restrict__ V, ushort* __restrict__ VBFB,
    const float* __restrict__ RBF, const float* __restrict__ UNITFC,
    const int* __restrict__ SRCS, const int* __restrict__ OFF,
    const float* __restrict__ rbfw, const float* __restrict__ rbfb)
{
    int a = blockIdx.x;
    int tid = threadIdx.x;
    int g = tid >> 6;          // wave role: 0=ds, 1=v*dvv, 2=unit*dvs
    int c0 = 2 * (tid & 63);   // channel pair within section

    float2 w[RDIM];
    const float* wc = rbfw + g*128 + c0;
    #pragma unroll
    for (int r = 0; r < RDIM; r++) { w[r].x = wc[r*384]; w[r].y = wc[r*384 + 1]; }
    float2 bb; bb.x = rbfb[g*128 + c0]; bb.y = rbfb[g*128 + c0 + 1];

    __shared__ int sSrc[64];
    __shared__ float4 sRBF[320];
    __shared__ float4 sUFC[64];
    __shared__ float avs[3][128];

    int beg = OFF[a], end = OFF[a + 1];
    float2 d; d.x = 0.f; d.y = 0.f;
    float2 A0, A1, A2v;
    A0.x=A0.y=A1.x=A1.y=A2v.x=A2v.y=0.f;

    for (int p0 = beg; p0 < end; p0 += 64) {
        int n = end - p0; if (n > 64) n = 64;
        __syncthreads();
        if (tid < n) sSrc[tid] = SRCS[p0 + tid];
        for (int i = tid; i < n; i += 192)
            sUFC[i] = *(const float4*)(UNITFC + (size_t)(p0 + i) * 4);
        {
            const float4* rsrc = (const float4*)(RBF + (size_t)p0 * RDIM);
            for (int i = tid; i < n*5; i += 192) sRBF[i] = rsrc[i];
        }
        __syncthreads();

        uint phA[4], u0A[4], u1A[4], u2A[4];
        uint phB[4], u0B[4], u1B[4], u2B[4];
        uint phC[4], u0C[4], u1C[4], u2C[4];

        auto grpLoad = [&](int base, uint* ph, uint* u0, uint* u1, uint* u2) {
            #pragma unroll
            for (int j = 0; j < 4; j++) {
                int q = base + j;
                int src = sSrc[(q < n) ? q : 0];
                size_t pb = (size_t)src * 128;
                ph[j] = *(const uint*)&PHIB[(size_t)src*384 + g*128 + c0];
                if (g == 1) {
                    u0[j] = *(const uint*)&VBFA[pb + c0];
                    u1[j] = *(const uint*)&VBFA[pb + VPLANE + c0];
                    u2[j] = *(const uint*)&VBFA[pb + 2*VPLANE + c0];
                }
            }
        };
        auto grpComp = [&](int base, uint* ph, uint* u0, uint* u1, uint* u2) {
            #pragma unroll
            for (int j = 0; j < 4; j++) {
                int q = base + j;
                if (q >= n) break;
                float4 r0 = sRBF[q*5+0], r1 = sRBF[q*5+1], r2 = sRBF[q*5+2],
                       r3 = sRBF[q*5+3], r4 = sRBF[q*5+4];
                float4 ufc = sUFC[q];
                float2 f = bb;
                f.x += r0.x*w[0].x;   f.y += r0.x*w[0].y;
                f.x += r0.y*w[1].x;   f.y += r0.y*w[1].y;
                f.x += r0.z*w[2].x;   f.y += r0.z*w[2].y;
                f.x += r0.w*w[3].x;   f.y += r0.w*w[3].y;
                f.x += r1.x*w[4].x;   f.y += r1.x*w[4].y;
                f.x += r1.y*w[5].x;   f.y += r1.y*w[5].y;
                f.x += r1.z*w[6].x;   f.y += r1.z*w[6].y;
                f.x += r1.w*w[7].x;   f.y += r1.w*w[7].y;
                f.x += r2.x*w[8].x;   f.y += r2.x*w[8].y;
                f.x += r2.y*w[9].x;   f.y += r2.y*w[9].y;
                f.x += r2.z*w[10].x;  f.y += r2.z*w[10].y;
                f.x += r2.w*w[11].x;  f.y += r2.w*w[11].y;
                f.x += r3.x*w[12].x;  f.y += r3.x*w[12].y;
                f.x += r3.y*w[13].x;  f.y += r3.y*w[13].y;
                f.x += r3.z*w[14].x;  f.y += r3.z*w[14].y;
                f.x += r3.w*w[15].x;  f.y += r3.w*w[15].y;
                f.x += r4.x*w[16].x;  f.y += r4.x*w[16].y;
                f.x += r4.y*w[17].x;  f.y += r4.y*w[17].y;
                f.x += r4.z*w[18].x;  f.y += r4.z*w[18].y;
                f.x += r4.w*w[19].x;  f.y += r4.w*w[19].y;
                uint up = ph[j];
                float m0 = __uint_as_float(up << 16)         * (f.x * ufc.w);
                float m1 = __uint_as_float(up & 0xffff0000u) * (f.y * ufc.w);
                if (g == 0) {
                    d.x += m0; d.y += m1;
                } else if (g == 1) {
                    A0.x  += __uint_as_float(u0[j] << 16)         * m0;
                    A0.y  += __uint_as_float(u0[j] & 0xffff0000u) * m1;
                    A1.x  += __uint_as_float(u1[j] << 16)         * m0;
                    A1.y  += __uint_as_float(u1[j] & 0xffff0000u) * m1;
                    A2v.x += __uint_as_float(u2[j] << 16)         * m0;
                    A2v.y += __uint_as_float(u2[j] & 0xffff0000u) * m1;
                } else {
                    A0.x  += ufc.x * m0; A0.y  += ufc.x * m1;
                    A1.x  += ufc.y * m0; A1.y  += ufc.y * m1;
                    A2v.x += ufc.z * m0; A2v.y += ufc.z * m1;
                }
            }
        };

        grpLoad(0, phA, u0A, u1A, u2A);
        grpLoad(4, phB, u0B, u1B, u2B);
        grpLoad(8, phC, u0C, u1C, u2C);
        for (int q0 = 0; q0 < n; q0 += 12) {
            grpComp(q0,      phA, u0A, u1A, u2A);
            grpLoad(q0 + 12, phA, u0A, u1A, u2A);
            grpComp(q0 + 4,  phB, u0B, u1B, u2B);
            grpLoad(q0 + 16, phB, u0B, u1B, u2B);
            grpComp(q0 + 8,  phC, u0C, u1C, u2C);
            grpLoad(q0 + 20, phC, u0C, u1C, u2C);
        }
    }

    if (g == 1) {
        avs[0][c0] = A0.x;  avs[0][c0+1] = A0.y;
        avs[1][c0] = A1.x;  avs[1][c0+1] = A1.y;
        avs[2][c0] = A2v.x; avs[2][c0+1] = A2v.y;
    }
    __syncthreads();
    if (g == 0) {
        size_t sb = (size_t)a*128 + c0;
        float2 s2 = *(float2*)&S[sb];
        s2.x += d.x; s2.y += d.y;
        *(float2*)&S[sb] = s2;
        SBF[sb] = f2bf(s2.x); SBF[sb+1] = f2bf(s2.y);
    } else if (g == 2) {
        float own0[3] = {A0.x, A1.x, A2v.x};
        float own1[3] = {A0.y, A1.y, A2v.y};
        #pragma unroll
        for (int c = 0; c < 3; c++) {
            size_t vb = (size_t)c*VPLANE + (size_t)a*128 + c0;
            float2 vi = *(const float2*)&V[vb];
            vi.x += avs[c][c0]     + own0[c];
            vi.y += avs[c][c0 + 1] + own1[c];
            *(float2*)&V[vb] = vi;
            VBFB[vb] = f2bf(vi.x); VBFB[vb+1] = f2bf(vi.y);
        }
    }
}

// ---------------- fused update: uv/vv GEMM + vvdot + a-MLP + s/v update ----------------
__global__ __launch_bounds__(256) void k_upd(
    const ushort* __restrict__ VBFB, const ushort* __restrict__ UVT,
    const ushort* __restrict__ SBF_in,
    const ushort* __restrict__ A1T, const float* __restrict__ a1b,
    const ushort* __restrict__ A2T, const float* __restrict__ a2b,
    float* __restrict__ S, ushort* __restrict__ SBF,
    float* __restrict__ V, ushort* __restrict__ VBFA)
{
    int tid = threadIdx.x;
    int w = tid >> 6, l = tid & 63;
    int bm = blockIdx.x * 16;
    int lrow = l & 15, lk = (l >> 4) * 8;
    __shared__ ushort sVVN[16][136];
    __shared__ ushort Hs[16][136];

    f32x4 au[3][2], av[3][2];
    #pragma unroll
    for (int c = 0; c < 3; c++)
        #pragma unroll
        for (int t = 0; t < 2; t++) {
            au[c][t] = (f32x4){0.f,0.f,0.f,0.f};
            av[c][t] = (f32x4){0.f,0.f,0.f,0.f};
        }
    #pragma unroll
    for (int k0 = 0; k0 < 128; k0 += 32) {
        bf16x8 af[3];
        #pragma unroll
        for (int c = 0; c < 3; c++)
            af[c] = *(const bf16x8*)&VBFB[(size_t)c*VPLANE + (size_t)(bm + lrow)*128 + k0 + lk];
        #pragma unroll
        for (int t = 0; t < 2; t++) {
            int nu = (2*w + t)*16 + lrow;
            bf16x8 bu = *(const bf16x8*)&UVT[(size_t)nu*128 + k0 + lk];
            bf16x8 bv = *(const bf16x8*)&UVT[(size_t)(nu + 128)*128 + k0 + lk];
            #pragma unroll
            for (int c = 0; c < 3; c++) {
                au[c][t] = __builtin_amdgcn_mfma_f32_16x16x32_bf16(af[c], bu, au[c][t], 0, 0, 0);
                av[c][t] = __builtin_amdgcn_mfma_f32_16x16x32_bf16(af[c], bv, av[c][t], 0, 0, 0);
            }
        }
    }
    float dotr[2][4], uvr[3][2][4];
    #pragma unroll
    for (int t = 0; t < 2; t++) {
        int k = (2*w + t)*16 + lrow;
        #pragma unroll
        for (int j = 0; j < 4; j++) {
            int row = (l >> 4)*4 + j;
            float u0 = au[0][t][j], u1 = au[1][t][j], u2 = au[2][t][j];
            float v0 = av[0][t][j], v1 = av[1][t][j], v2 = av[2][t][j];
            uvr[0][t][j] = u0; uvr[1][t][j] = u1; uvr[2][t][j] = u2;
            dotr[t][j] = u0*v0 + u1*v1 + u2*v2;
            sVVN[row][k] = f2bf(sqrtf(v0*v0 + v1*v1 + v2*v2 + EPSV));
        }
    }
    __syncthreads();

    f32x4 acc[2] = {{0.f,0.f,0.f,0.f},{0.f,0.f,0.f,0.f}};
    #pragma unroll
    for (int k0 = 0; k0 < 256; k0 += 32) {
        bf16x8 af;
        if (k0 < 128) af = *(const bf16x8*)&SBF_in[(size_t)(bm + lrow)*128 + k0 + lk];
        else          af = *(const bf16x8*)&sVVN[lrow][k0 + lk - 128];
        #pragma unroll
        for (int t = 0; t < 2; t++) {
            int n = (2*w + t)*16 + lrow;
            bf16x8 bf = *(const bf16x8*)&A1T[(size_t)n*256 + k0 + lk];
            acc[t] = __builtin_amdgcn_mfma_f32_16x16x32_bf16(af, bf, acc[t], 0, 0, 0);
        }
    }
    #pragma unroll
    for (int t = 0; t < 2; t++) {
        int col = (2*w + t)*16 + lrow;
        float bv = a1b[col];
        #pragma unroll
        for (int j = 0; j < 4; j++) {
            int row = (l >> 4)*4 + j;
            float val = acc[t][j] + bv;
            val = val / (1.0f + __expf(-val));
            Hs[row][col] = f2bf(val);
        }
    }
    __syncthreads();

    f32x4 c_vv[2], c_sv[2], c_ss[2];
    #pragma unroll
    for (int t = 0; t < 2; t++) {
        c_vv[t] = (f32x4){0.f,0.f,0.f,0.f};
        c_sv[t] = (f32x4){0.f,0.f,0.f,0.f};
        c_ss[t] = (f32x4){0.f,0.f,0.f,0.f};
    }
    #pragma unroll
    for (int k0 = 0; k0 < 128; k0 += 32) {
        bf16x8 af = *(const bf16x8*)&Hs[lrow][k0 + lk];
        #pragma unroll
        for (int t = 0; t < 2; t++) {
            int n0 = (2*w + t)*16 + lrow;
            bf16x8 b0 = *(const bf16x8*)&A2T[(size_t)n0*128 + k0 + lk];
            bf16x8 b1 = *(const bf16x8*)&A2T[(size_t)(n0 + 128)*128 + k0 + lk];
            bf16x8 b2 = *(const bf16x8*)&A2T[(size_t)(n0 + 256)*128 + k0 + lk];
            c_vv[t] = __builtin_amdgcn_mfma_f32_16x16x32_bf16(af, b0, c_vv[t], 0, 0, 0);
            c_sv[t] = __builtin_amdgcn_mfma_f32_16x16x32_bf16(af, b1, c_sv[t], 0, 0, 0);
            c_ss[t] = __builtin_amdgcn_mfma_f32_16x16x32_bf16(af, b2, c_ss[t], 0, 0, 0);
        }
    }
    #pragma unroll
    for (int t = 0; t < 2; t++) {
        int k = (2*w + t)*16 + lrow;
        float b_vv = a2b[k], b_sv = a2b[128 + k], b_ss = a2b[256 + k];
        #pragma unroll
        for (int j = 0; j < 4; j++) {
            int a = bm + (l >> 4)*4 + j;
            size_t base = (size_t)a*128 + k;
            float vv = c_vv[t][j] + b_vv;
            float sv = c_sv[t][j] + b_sv;
            float ss = c_ss[t][j] + b_ss;
            float sn = S[base] + ss + sv * dotr[t][j];
            S[base] = sn; SBF[base] = f2bf(sn);
            #pragma unroll
            for (int c = 0; c < 3; c++) {
                size_t vb = (size_t)c*VPLANE + base;
                float nv = V[vb] + vv * uvr[c][t][j];
                V[vb] = nv; VBFA[vb] = f2bf(nv);
            }
        }
    }
}

// ---------------- fused readout + molecule accumulation ----------------
__global__ __launch_bounds__(64) void k_readout(
    const ushort* __restrict__ SBF, const ushort* __restrict__ OW1T,
    const float* __restrict__ b1, const float* __restrict__ w2,
    const float* __restrict__ b2v, const int* __restrict__ mol,
    float* __restrict__ out)
{
    int l = threadIdx.x;
    int bm = blockIdx.x * 16;
    int lrow = l & 15, lk = (l >> 4) * 8;
    __shared__ float Hs[16][132];

    f32x4 acc[8];
    #pragma unroll
    for (int t = 0; t < 8; t++) acc[t] = (f32x4){0.f,0.f,0.f,0.f};
    #pragma unroll
    for (int k0 = 0; k0 < 128; k0 += 32) {
        bf16x8 af = *(const bf16x8*)&SBF[(size_t)(bm + lrow)*128 + k0 + lk];
        #pragma unroll
        for (int t = 0; t < 8; t++) {
            bf16x8 bf = *(const bf16x8*)&OW1T[(size_t)(t*16 + lrow)*128 + k0 + lk];
            acc[t] = __builtin_amdgcn_mfma_f32_16x16x32_bf16(af, bf, acc[t], 0, 0, 0);
        }
    }
    #pragma unroll
    for (int t = 0; t < 8; t++) {
        int col = t*16 + lrow;
        float bv = b1[col];
        #pragma unroll
        for (int j = 0; j < 4; j++) {
            int row = (l >> 4)*4 + j;
            float val = acc[t][j] + bv;
            Hs[row][col] = val / (1.0f + __expf(-val));
        }
    }
    __syncthreads();
    if (l < 16) {
        float s = b2v[0];
        #pragma unroll 8
        for (int k = 0; k < 128; k++) s += Hs[l][k] * w2[k];
        atomicAdd(&out[mol[bm + l]], s);
    }
}

extern "C" void kernel_launch(void* const* d_in, const int* in_sizes, int n_in,
                              void* d_out, int out_size, void* d_ws, size_t ws_size,
                              hipStream_t stream) {
    const int*   z      = (const int*)d_in[0];
    const float* pos    = (const float*)d_in[1];
    const int*   esrc   = (const int*)d_in[2];
    const int*   edst   = (const int*)d_in[3];
    const int*   mol    = (const int*)d_in[4];
    const float* embed  = (const float*)d_in[5];
    const float* msg_w1 = (const float*)d_in[6];
    const float* msg_b1 = (const float*)d_in[7];
    const float* msg_w2 = (const float*)d_in[8];
    const float* msg_b2 = (const float*)d_in[9];
    const float* rbf_w  = (const float*)d_in[10];
    const float* rbf_b  = (const float*)d_in[11];
    const float* upd_u  = (const float*)d_in[12];
    const float* upd_v  = (const float*)d_in[13];
    const float* upd_a1 = (const float*)d_in[14];
    const float* upd_a1b= (const float*)d_in[15];
    const float* upd_a2 = (const float*)d_in[16];
    const float* upd_a2b= (const float*)d_in[17];
    const float* out_w1 = (const float*)d_in[18];
    const float* out_b1 = (const float*)d_in[19];
    const float* out_w2 = (const float*)d_in[20];
    const float* out_b2 = (const float*)d_in[21];

    float* ws = (float*)d_ws;
    float* S      = ws; ws += 1048576;     // 8192*128 f32
    float* V      = ws; ws += 3145728;     // 3 planes [c][a][k]
    float* RBF    = ws; ws += 5242880;     // sorted
    float* UNITFC = ws; ws += 1048576;     // sorted
    ushort* PHIB  = (ushort*)ws; ws += 1572864;   // 8192*384
    ushort* VBFA  = (ushort*)ws; ws += 1572864;   // v bf16 planes (gather)
    ushort* VBFB  = (ushort*)ws; ws += 1572864;   // post-agg v bf16 planes (GEMM A)
    ushort* SBF   = (ushort*)ws; ws += 524288;
    ushort* WT    = (ushort*)ws; ws += 278528;
    int* CNT  = (int*)ws;
    int* OFF  = CNT + 8192;
    int* CUR  = OFF + 8193;
    int* SRCS = CUR + 8192;

    hipMemsetAsync(V, 0, 3145728 * sizeof(float), stream);
    hipMemsetAsync(VBFA, 0, 3145728 * sizeof(ushort), stream);
    hipMemsetAsync(CNT, 0, 8192 * sizeof(int), stream);
    hipMemsetAsync(d_out, 0, N_MOL * sizeof(float), stream);

    k_wconv<<<2176, 256, 0, stream>>>(msg_w1, msg_w2, upd_u, upd_v, upd_a1, upd_a2, out_w1, WT);
    k_embed<<<4096, 256, 0, stream>>>(z, embed, S, SBF);
    k_hist<<<1024, 256, 0, stream>>>(edst, CNT);
    k_scan<<<1, 1024, 0, stream>>>(CNT, OFF, CUR);
    k_edges<<<1024, 256, 0, stream>>>(pos, esrc, edst, CUR, RBF, UNITFC, SRCS);

    for (int l = 0; l < LLAYERS; l++) {
        const ushort* W1T = WT + l*16384;
        const ushort* W2T = WT + 49152  + l*49152;
        const ushort* UVT = WT + 196608 + l*32768;
        const ushort* A1T = WT + 294912 + l*32768;
        const ushort* A2T = WT + 393216 + l*49152;

        k_msg<<<512, 256, 0, stream>>>(SBF, W1T, msg_b1 + (size_t)l*128,
                                       W2T, msg_b2 + (size_t)l*384, PHIB);
        k_aggregate<<<8192, 192, 0, stream>>>(PHIB, VBFA, S, SBF, V, VBFB, RBF, UNITFC,
            SRCS, OFF, rbf_w + (size_t)l*20*384, rbf_b + (size_t)l*384);
        k_upd<<<512, 256, 0, stream>>>(VBFB, UVT, SBF, A1T, upd_a1b + (size_t)l*128,
            A2T, upd_a2b + (size_t)l*384, S, SBF, V, VBFA);
    }

    k_readout<<<512, 64, 0, stream>>>(SBF, WT + 540672, out_b1, out_w2, out_b2,
                                      mol, (float*)d_out);
}

// Round 11
// 654.849 us; speedup vs baseline: 1.0755x; 1.0755x over previous
//
#include <hip/hip_runtime.h>
#include <hip/hip_bf16.h>
#include <math.h>

#define N_ATOMS 8192
#define N_EDGES 262144
#define N_MOL   128
#define FDIM    128
#define RDIM    20
#define LLAYERS 3
#define CUTOFF  5.0f
#define EPSV    1e-8f
#define PI_F    3.14159265358979323846f

typedef __attribute__((ext_vector_type(8))) short bf16x8;
typedef __attribute__((ext_vector_type(4))) float f32x4;

#define VPLANE 1048576   // 8192*128 elements per component plane

__device__ __forceinline__ ushort f2bf(float x) {
    uint b = __float_as_uint(x);
    return (ushort)((b + 0x7fffu + ((b >> 16) & 1u)) >> 16);
}

// ---------------- weight convert+transpose (f32 KxN -> bf16 NxK) ----------------
__global__ void k_wconv(const float* __restrict__ w1, const float* __restrict__ w2,
                        const float* __restrict__ uu, const float* __restrict__ uvw,
                        const float* __restrict__ a1, const float* __restrict__ a2,
                        const float* __restrict__ ow1, ushort* __restrict__ WT) {
    int i = blockIdx.x * 256 + threadIdx.x;  // < 557056
    float v;
    if (i < 49152) {                          // W1T
        int idx = i; int l = idx >> 14; idx &= 16383;
        int n = idx >> 7, k = idx & 127;
        v = w1[l*16384 + k*128 + n];
    } else if (i < 196608) {                  // W2T
        int idx = i - 49152; int l = idx / 49152; idx -= l * 49152;
        int n = idx >> 7, k = idx & 127;
        v = w2[l*49152 + k*384 + n];
    } else if (i < 294912) {                  // UVT (u cols 0-127, v cols 128-255)
        int idx = i - 196608; int l = idx >> 15; idx &= 32767;
        int n = idx >> 7, k = idx & 127;
        v = (n < 128) ? uu[l*16384 + k*128 + n] : uvw[l*16384 + k*128 + (n-128)];
    } else if (i < 393216) {                  // A1T (128n x 256k)
        int idx = i - 294912; int l = idx >> 15; idx &= 32767;
        int n = idx >> 8, k = idx & 255;
        v = a1[l*32768 + k*128 + n];
    } else if (i < 540672) {                  // A2T
        int idx = i - 393216; int l = idx / 49152; idx -= l * 49152;
        int n = idx >> 7, k = idx & 127;
        v = a2[l*49152 + k*384 + n];
    } else {                                  // OW1T
        int idx = i - 540672;
        int n = idx >> 7, k = idx & 127;
        v = ow1[k*128 + n];
    }
    WT[i] = f2bf(v);
}

// ---------------- embed gather ----------------
__global__ void k_embed(const int* __restrict__ z, const float* __restrict__ embed,
                        float* __restrict__ S, ushort* __restrict__ SBF) {
    int i = blockIdx.x * 256 + threadIdx.x;
    int a = i >> 7, k = i & 127;
    float v = embed[(size_t)z[a] * FDIM + k];
    S[i] = v; SBF[i] = f2bf(v);
}

// ---------------- CSR build ----------------
__global__ void k_hist(const int* __restrict__ edst, int* __restrict__ CNT) {
    int e = blockIdx.x * 256 + threadIdx.x;
    if (e < N_EDGES) atomicAdd(&CNT[edst[e]], 1);
}

__global__ __launch_bounds__(1024) void k_scan(const int* __restrict__ CNT,
                                               int* __restrict__ OFF, int* __restrict__ CUR) {
    __shared__ int part[1024];
    int t = threadIdx.x;
    int loc[8];
    int run = 0;
    #pragma unroll
    for (int i = 0; i < 8; i++) { int c = CNT[t*8 + i]; loc[i] = run; run += c; }
    part[t] = run;
    __syncthreads();
    for (int off = 1; off < 1024; off <<= 1) {
        int v = 0;
        if (t >= off) v = part[t - off];
        __syncthreads();
        part[t] += v;
        __syncthreads();
    }
    int ebase = (t > 0) ? part[t-1] : 0;
    #pragma unroll
    for (int i = 0; i < 8; i++) { int o = ebase + loc[i]; OFF[t*8+i] = o; CUR[t*8+i] = o; }
    if (t == 1023) OFF[8192] = part[1023];
}

// ---------------- edge geometry + rbf, CSR-sorted (pos fused) ----------------
__global__ void k_edges(const float* __restrict__ pos, const int* __restrict__ esrc,
                        const int* __restrict__ edst, int* __restrict__ CUR,
                        float* __restrict__ RBF, float* __restrict__ UNITFC,
                        int* __restrict__ SRCS) {
    int e = blockIdx.x * 256 + threadIdx.x;
    if (e >= N_EDGES) return;
    int s = esrc[e], d = edst[e];
    int p = atomicAdd(&CUR[d], 1);
    float rx = pos[d*3+0] - pos[s*3+0];
    float ry = pos[d*3+1] - pos[s*3+1];
    float rz = pos[d*3+2] - pos[s*3+2];
    float dd = sqrtf(rx*rx + ry*ry + rz*rz + EPSV);
    float inv = 1.0f / dd;
    float fc = (dd < CUTOFF) ? 0.5f * (cosf(dd * (PI_F / CUTOFF)) + 1.0f) : 0.0f;
    float4 u4; u4.x = rx*inv; u4.y = ry*inv; u4.z = rz*inv; u4.w = fc;
    *(float4*)&UNITFC[(size_t)p*4] = u4;
    SRCS[p] = s;
    float rb[RDIM];
    #pragma unroll
    for (int r = 0; r < RDIM; r++) {
        float freq = (float)(r + 1) * (PI_F / CUTOFF);
        rb[r] = sinf(dd * freq) * inv;
    }
    float4* out = (float4*)&RBF[(size_t)p * RDIM];
    #pragma unroll
    for (int q = 0; q < 5; q++) {
        float4 o; o.x = rb[q*4]; o.y = rb[q*4+1]; o.z = rb[q*4+2]; o.w = rb[q*4+3];
        out[q] = o;
    }
}

// ---------------- fused message MLP (4 waves): PHIB = (silu(S@w1+b1))@w2+b2 ----------------
__global__ __launch_bounds__(256) void k_msg(
    const ushort* __restrict__ SBF, const ushort* __restrict__ W1T, const float* __restrict__ b1,
    const ushort* __restrict__ W2T, const float* __restrict__ b2, ushort* __restrict__ PHIB)
{
    int tid = threadIdx.x;
    int w = tid >> 6, l = tid & 63;
    int bm = blockIdx.x * 16;
    int lrow = l & 15, lk = (l >> 4) * 8;
    __shared__ ushort Hs[16][136];

    f32x4 acc[2] = {{0.f,0.f,0.f,0.f},{0.f,0.f,0.f,0.f}};
    #pragma unroll
    for (int k0 = 0; k0 < 128; k0 += 32) {
        bf16x8 af = *(const bf16x8*)&SBF[(size_t)(bm + lrow)*128 + k0 + lk];
        #pragma unroll
        for (int t = 0; t < 2; t++) {
            int n = (2*w + t)*16 + lrow;
            bf16x8 bf = *(const bf16x8*)&W1T[(size_t)n*128 + k0 + lk];
            acc[t] = __builtin_amdgcn_mfma_f32_16x16x32_bf16(af, bf, acc[t], 0, 0, 0);
        }
    }
    #pragma unroll
    for (int t = 0; t < 2; t++) {
        int col = (2*w + t)*16 + lrow;
        float bv = b1[col];
        #pragma unroll
        for (int j = 0; j < 4; j++) {
            int row = (l >> 4)*4 + j;
            float val = acc[t][j] + bv;
            val = val / (1.0f + __expf(-val));
            Hs[row][col] = f2bf(val);
        }
    }
    __syncthreads();

    f32x4 acc2[6];
    #pragma unroll
    for (int t = 0; t < 6; t++) acc2[t] = (f32x4){0.f,0.f,0.f,0.f};
    #pragma unroll
    for (int k0 = 0; k0 < 128; k0 += 32) {
        bf16x8 af = *(const bf16x8*)&Hs[lrow][k0 + lk];
        #pragma unroll
        for (int t = 0; t < 6; t++) {
            int n = (6*w + t)*16 + lrow;
            bf16x8 bf = *(const bf16x8*)&W2T[(size_t)n*128 + k0 + lk];
            acc2[t] = __builtin_amdgcn_mfma_f32_16x16x32_bf16(af, bf, acc2[t], 0, 0, 0);
        }
    }
    #pragma unroll
    for (int t = 0; t < 6; t++) {
        int col = (6*w + t)*16 + lrow;
        float bv = b2[col];
        #pragma unroll
        for (int j = 0; j < 4; j++) {
            int row = bm + (l >> 4)*4 + j;
            PHIB[(size_t)row*384 + col] = f2bf(acc2[t][j] + bv);
        }
    }
}

// ---------------- edge aggregation: 4 atoms/block, depth-2 guarded pipeline ----------------
template<bool L0>
__global__ __launch_bounds__(192) void k_aggregate(
    const ushort* __restrict__ PHIB, const ushort* __restrict__ VBFA,
    float* __restrict__ S, ushort* __restrict__ SBF,
    float* __restrict__ V, ushort* __restrict__ VBFB,
    const float* __restrict__ RBF, const float* __restrict__ UNITFC,
    const int* __restrict__ SRCS, const int* __restrict__ OFF,
    const float* __restrict__ rbfw, const float* __restrict__ rbfb)
{
    int tid = threadIdx.x;
    int g = tid >> 6;          // wave role: 0=ds, 1=v*dvv, 2=unit*dvs
    int c0 = 2 * (tid & 63);   // channel pair within section

    float2 w[RDIM];
    const float* wc = rbfw + g*128 + c0;
    #pragma unroll
    for (int r = 0; r < RDIM; r++) { w[r].x = wc[r*384]; w[r].y = wc[r*384 + 1]; }
    float2 bb; bb.x = rbfb[g*128 + c0]; bb.y = rbfb[g*128 + c0 + 1];

    __shared__ int sSrc[64];
    __shared__ float4 sRBF[320];
    __shared__ float4 sUFC[64];
    __shared__ float avs[3][128];

    for (int ai = 0; ai < 4; ai++) {
        int a = blockIdx.x * 4 + ai;
        int beg = OFF[a], end = OFF[a + 1];
        float2 d; d.x = 0.f; d.y = 0.f;
        float2 A0, A1, A2v;
        A0.x=A0.y=A1.x=A1.y=A2v.x=A2v.y=0.f;

        for (int p0 = beg; p0 < end; p0 += 64) {
            int n = end - p0; if (n > 64) n = 64;
            __syncthreads();
            if (tid < n) sSrc[tid] = SRCS[p0 + tid];
            for (int i = tid; i < n; i += 192)
                sUFC[i] = *(const float4*)(UNITFC + (size_t)(p0 + i) * 4);
            {
                const float4* rsrc = (const float4*)(RBF + (size_t)p0 * RDIM);
                for (int i = tid; i < n*5; i += 192) sRBF[i] = rsrc[i];
            }
            __syncthreads();

            if (L0 && g == 1) continue;   // layer 0: v == 0, g1 contributes nothing

            uint phA[4], u0A[4], u1A[4], u2A[4];
            uint phB[4], u0B[4], u1B[4], u2B[4];

            auto grpLoad = [&](int base, uint* ph, uint* u0, uint* u1, uint* u2) {
                #pragma unroll
                for (int j = 0; j < 4; j++) {
                    int q = base + j;
                    int src = sSrc[(q < n) ? q : 0];
                    size_t pb = (size_t)src * 128;
                    ph[j] = *(const uint*)&PHIB[(size_t)src*384 + g*128 + c0];
                    if (!L0 && g == 1) {
                        u0[j] = *(const uint*)&VBFA[pb + c0];
                        u1[j] = *(const uint*)&VBFA[pb + VPLANE + c0];
                        u2[j] = *(const uint*)&VBFA[pb + 2*VPLANE + c0];
                    }
                }
            };
            grpLoad(0, phA, u0A, u1A, u2A);
            for (int q0 = 0; q0 < n; q0 += 4) {
                if (q0 + 4 < n) grpLoad(q0 + 4, phB, u0B, u1B, u2B);
                #pragma unroll
                for (int j = 0; j < 4; j++) {
                    int q = q0 + j;
                    if (q >= n) break;
                    float4 r0 = sRBF[q*5+0], r1 = sRBF[q*5+1], r2 = sRBF[q*5+2],
                           r3 = sRBF[q*5+3], r4 = sRBF[q*5+4];
                    float4 ufc = sUFC[q];
                    float2 f = bb;
                    f.x += r0.x*w[0].x;   f.y += r0.x*w[0].y;
                    f.x += r0.y*w[1].x;   f.y += r0.y*w[1].y;
                    f.x += r0.z*w[2].x;   f.y += r0.z*w[2].y;
                    f.x += r0.w*w[3].x;   f.y += r0.w*w[3].y;
                    f.x += r1.x*w[4].x;   f.y += r1.x*w[4].y;
                    f.x += r1.y*w[5].x;   f.y += r1.y*w[5].y;
                    f.x += r1.z*w[6].x;   f.y += r1.z*w[6].y;
                    f.x += r1.w*w[7].x;   f.y += r1.w*w[7].y;
                    f.x += r2.x*w[8].x;   f.y += r2.x*w[8].y;
                    f.x += r2.y*w[9].x;   f.y += r2.y*w[9].y;
                    f.x += r2.z*w[10].x;  f.y += r2.z*w[10].y;
                    f.x += r2.w*w[11].x;  f.y += r2.w*w[11].y;
                    f.x += r3.x*w[12].x;  f.y += r3.x*w[12].y;
                    f.x += r3.y*w[13].x;  f.y += r3.y*w[13].y;
                    f.x += r3.z*w[14].x;  f.y += r3.z*w[14].y;
                    f.x += r3.w*w[15].x;  f.y += r3.w*w[15].y;
                    f.x += r4.x*w[16].x;  f.y += r4.x*w[16].y;
                    f.x += r4.y*w[17].x;  f.y += r4.y*w[17].y;
                    f.x += r4.z*w[18].x;  f.y += r4.z*w[18].y;
                    f.x += r4.w*w[19].x;  f.y += r4.w*w[19].y;
                    uint up = phA[j];
                    float m0 = __uint_as_float(up << 16)         * (f.x * ufc.w);
                    float m1 = __uint_as_float(up & 0xffff0000u) * (f.y * ufc.w);
                    if (g == 0) {
                        d.x += m0; d.y += m1;
                    } else if (g == 1) {
                        A0.x  += __uint_as_float(u0A[j] << 16)         * m0;
                        A0.y  += __uint_as_float(u0A[j] & 0xffff0000u) * m1;
                        A1.x  += __uint_as_float(u1A[j] << 16)         * m0;
                        A1.y  += __uint_as_float(u1A[j] & 0xffff0000u) * m1;
                        A2v.x += __uint_as_float(u2A[j] << 16)         * m0;
                        A2v.y += __uint_as_float(u2A[j] & 0xffff0000u) * m1;
                    } else {
                        A0.x  += ufc.x * m0; A0.y  += ufc.x * m1;
                        A1.x  += ufc.y * m0; A1.y  += ufc.y * m1;
                        A2v.x += ufc.z * m0; A2v.y += ufc.z * m1;
                    }
                }
                #pragma unroll
                for (int j = 0; j < 4; j++) {
                    phA[j] = phB[j]; u0A[j] = u0B[j]; u1A[j] = u1B[j]; u2A[j] = u2B[j];
                }
            }
        }

        if (g == 1) {
            avs[0][c0] = A0.x;  avs[0][c0+1] = A0.y;
            avs[1][c0] = A1.x;  avs[1][c0+1] = A1.y;
            avs[2][c0] = A2v.x; avs[2][c0+1] = A2v.y;
        }
        __syncthreads();
        if (g == 0) {
            size_t sb = (size_t)a*128 + c0;
            float2 s2 = *(float2*)&S[sb];
            s2.x += d.x; s2.y += d.y;
            *(float2*)&S[sb] = s2;
            SBF[sb] = f2bf(s2.x); SBF[sb+1] = f2bf(s2.y);
        } else if (g == 2) {
            float own0[3] = {A0.x, A1.x, A2v.x};
            float own1[3] = {A0.y, A1.y, A2v.y};
            #pragma unroll
            for (int c = 0; c < 3; c++) {
                size_t vb = (size_t)c*VPLANE + (size_t)a*128 + c0;
                float2 vi;
                if (L0) { vi.x = 0.f; vi.y = 0.f; }
                else    vi = *(const float2*)&V[vb];
                vi.x += avs[c][c0]     + own0[c];
                vi.y += avs[c][c0 + 1] + own1[c];
                *(float2*)&V[vb] = vi;
                VBFB[vb] = f2bf(vi.x); VBFB[vb+1] = f2bf(vi.y);
            }
        }
    }
}

// ---------------- fused update: uv/vv GEMM + vvdot + a-MLP + s/v update ----------------
__global__ __launch_bounds__(256) void k_upd(
    const ushort* __restrict__ VBFB, const ushort* __restrict__ UVT,
    const ushort* __restrict__ SBF_in,
    const ushort* __restrict__ A1T, const float* __restrict__ a1b,
    const ushort* __restrict__ A2T, const float* __restrict__ a2b,
    float* __restrict__ S, ushort* __restrict__ SBF,
    float* __restrict__ V, ushort* __restrict__ VBFA)
{
    int tid = threadIdx.x;
    int w = tid >> 6, l = tid & 63;
    int bm = blockIdx.x * 16;
    int lrow = l & 15, lk = (l >> 4) * 8;
    __shared__ ushort sVVN[16][136];
    __shared__ ushort Hs[16][136];

    f32x4 au[3][2], av[3][2];
    #pragma unroll
    for (int c = 0; c < 3; c++)
        #pragma unroll
        for (int t = 0; t < 2; t++) {
            au[c][t] = (f32x4){0.f,0.f,0.f,0.f};
            av[c][t] = (f32x4){0.f,0.f,0.f,0.f};
        }
    #pragma unroll
    for (int k0 = 0; k0 < 128; k0 += 32) {
        bf16x8 af[3];
        #pragma unroll
        for (int c = 0; c < 3; c++)
            af[c] = *(const bf16x8*)&VBFB[(size_t)c*VPLANE + (size_t)(bm + lrow)*128 + k0 + lk];
        #pragma unroll
        for (int t = 0; t < 2; t++) {
            int nu = (2*w + t)*16 + lrow;
            bf16x8 bu = *(const bf16x8*)&UVT[(size_t)nu*128 + k0 + lk];
            bf16x8 bv = *(const bf16x8*)&UVT[(size_t)(nu + 128)*128 + k0 + lk];
            #pragma unroll
            for (int c = 0; c < 3; c++) {
                au[c][t] = __builtin_amdgcn_mfma_f32_16x16x32_bf16(af[c], bu, au[c][t], 0, 0, 0);
                av[c][t] = __builtin_amdgcn_mfma_f32_16x16x32_bf16(af[c], bv, av[c][t], 0, 0, 0);
            }
        }
    }
    float dotr[2][4], uvr[3][2][4];
    #pragma unroll
    for (int t = 0; t < 2; t++) {
        int k = (2*w + t)*16 + lrow;
        #pragma unroll
        for (int j = 0; j < 4; j++) {
            int row = (l >> 4)*4 + j;
            float u0 = au[0][t][j], u1 = au[1][t][j], u2 = au[2][t][j];
            float v0 = av[0][t][j], v1 = av[1][t][j], v2 = av[2][t][j];
            uvr[0][t][j] = u0; uvr[1][t][j] = u1; uvr[2][t][j] = u2;
            dotr[t][j] = u0*v0 + u1*v1 + u2*v2;
            sVVN[row][k] = f2bf(sqrtf(v0*v0 + v1*v1 + v2*v2 + EPSV));
        }
    }
    __syncthreads();

    f32x4 acc[2] = {{0.f,0.f,0.f,0.f},{0.f,0.f,0.f,0.f}};
    #pragma unroll
    for (int k0 = 0; k0 < 256; k0 += 32) {
        bf16x8 af;
        if (k0 < 128) af = *(const bf16x8*)&SBF_in[(size_t)(bm + lrow)*128 + k0 + lk];
        else          af = *(const bf16x8*)&sVVN[lrow][k0 + lk - 128];
        #pragma unroll
        for (int t = 0; t < 2; t++) {
            int n = (2*w + t)*16 + lrow;
            bf16x8 bf = *(const bf16x8*)&A1T[(size_t)n*256 + k0 + lk];
            acc[t] = __builtin_amdgcn_mfma_f32_16x16x32_bf16(af, bf, acc[t], 0, 0, 0);
        }
    }
    #pragma unroll
    for (int t = 0; t < 2; t++) {
        int col = (2*w + t)*16 + lrow;
        float bv = a1b[col];
        #pragma unroll
        for (int j = 0; j < 4; j++) {
            int row = (l >> 4)*4 + j;
            float val = acc[t][j] + bv;
            val = val / (1.0f + __expf(-val));
            Hs[row][col] = f2bf(val);
        }
    }
    __syncthreads();

    f32x4 c_vv[2], c_sv[2], c_ss[2];
    #pragma unroll
    for (int t = 0; t < 2; t++) {
        c_vv[t] = (f32x4){0.f,0.f,0.f,0.f};
        c_sv[t] = (f32x4){0.f,0.f,0.f,0.f};
        c_ss[t] = (f32x4){0.f,0.f,0.f,0.f};
    }
    #pragma unroll
    for (int k0 = 0; k0 < 128; k0 += 32) {
        bf16x8 af = *(const bf16x8*)&Hs[lrow][k0 + lk];
        #pragma unroll
        for (int t = 0; t < 2; t++) {
            int n0 = (2*w + t)*16 + lrow;
            bf16x8 b0 = *(const bf16x8*)&A2T[(size_t)n0*128 + k0 + lk];
            bf16x8 b1 = *(const bf16x8*)&A2T[(size_t)(n0 + 128)*128 + k0 + lk];
            bf16x8 b2 = *(const bf16x8*)&A2T[(size_t)(n0 + 256)*128 + k0 + lk];
            c_vv[t] = __builtin_amdgcn_mfma_f32_16x16x32_bf16(af, b0, c_vv[t], 0, 0, 0);
            c_sv[t] = __builtin_amdgcn_mfma_f32_16x16x32_bf16(af, b1, c_sv[t], 0, 0, 0);
            c_ss[t] = __builtin_amdgcn_mfma_f32_16x16x32_bf16(af, b2, c_ss[t], 0, 0, 0);
        }
    }
    #pragma unroll
    for (int t = 0; t < 2; t++) {
        int k = (2*w + t)*16 + lrow;
        float b_vv = a2b[k], b_sv = a2b[128 + k], b_ss = a2b[256 + k];
        #pragma unroll
        for (int j = 0; j < 4; j++) {
            int a = bm + (l >> 4)*4 + j;
            size_t base = (size_t)a*128 + k;
            float vv = c_vv[t][j] + b_vv;
            float sv = c_sv[t][j] + b_sv;
            float ss = c_ss[t][j] + b_ss;
            float sn = S[base] + ss + sv * dotr[t][j];
            S[base] = sn; SBF[base] = f2bf(sn);
            #pragma unroll
            for (int c = 0; c < 3; c++) {
                size_t vb = (size_t)c*VPLANE + base;
                float nv = V[vb] + vv * uvr[c][t][j];
                V[vb] = nv; VBFA[vb] = f2bf(nv);
            }
        }
    }
}

// ---------------- fused readout + molecule accumulation ----------------
__global__ __launch_bounds__(64) void k_readout(
    const ushort* __restrict__ SBF, const ushort* __restrict__ OW1T,
    const float* __restrict__ b1, const float* __restrict__ w2,
    const float* __restrict__ b2v, const int* __restrict__ mol,
    float* __restrict__ out)
{
    int l = threadIdx.x;
    int bm = blockIdx.x * 16;
    int lrow = l & 15, lk = (l >> 4) * 8;
    __shared__ float Hs[16][132];

    f32x4 acc[8];
    #pragma unroll
    for (int t = 0; t < 8; t++) acc[t] = (f32x4){0.f,0.f,0.f,0.f};
    #pragma unroll
    for (int k0 = 0; k0 < 128; k0 += 32) {
        bf16x8 af = *(const bf16x8*)&SBF[(size_t)(bm + lrow)*128 + k0 + lk];
        #pragma unroll
        for (int t = 0; t < 8; t++) {
            bf16x8 bf = *(const bf16x8*)&OW1T[(size_t)(t*16 + lrow)*128 + k0 + lk];
            acc[t] = __builtin_amdgcn_mfma_f32_16x16x32_bf16(af, bf, acc[t], 0, 0, 0);
        }
    }
    #pragma unroll
    for (int t = 0; t < 8; t++) {
        int col = t*16 + lrow;
        float bv = b1[col];
        #pragma unroll
        for (int j = 0; j < 4; j++) {
            int row = (l >> 4)*4 + j;
            float val = acc[t][j] + bv;
            Hs[row][col] = val / (1.0f + __expf(-val));
        }
    }
    __syncthreads();
    if (l < 16) {
        float s = b2v[0];
        #pragma unroll 8
        for (int k = 0; k < 128; k++) s += Hs[l][k] * w2[k];
        atomicAdd(&out[mol[bm + l]], s);
    }
}

extern "C" void kernel_launch(void* const* d_in, const int* in_sizes, int n_in,
                              void* d_out, int out_size, void* d_ws, size_t ws_size,
                              hipStream_t stream) {
    const int*   z      = (const int*)d_in[0];
    const float* pos    = (const float*)d_in[1];
    const int*   esrc   = (const int*)d_in[2];
    const int*   edst   = (const int*)d_in[3];
    const int*   mol    = (const int*)d_in[4];
    const float* embed  = (const float*)d_in[5];
    const float* msg_w1 = (const float*)d_in[6];
    const float* msg_b1 = (const float*)d_in[7];
    const float* msg_w2 = (const float*)d_in[8];
    const float* msg_b2 = (const float*)d_in[9];
    const float* rbf_w  = (const float*)d_in[10];
    const float* rbf_b  = (const float*)d_in[11];
    const float* upd_u  = (const float*)d_in[12];
    const float* upd_v  = (const float*)d_in[13];
    const float* upd_a1 = (const float*)d_in[14];
    const float* upd_a1b= (const float*)d_in[15];
    const float* upd_a2 = (const float*)d_in[16];
    const float* upd_a2b= (const float*)d_in[17];
    const float* out_w1 = (const float*)d_in[18];
    const float* out_b1 = (const float*)d_in[19];
    const float* out_w2 = (const float*)d_in[20];
    const float* out_b2 = (const float*)d_in[21];

    float* ws = (float*)d_ws;
    float* S      = ws; ws += 1048576;     // 8192*128 f32
    float* V      = ws; ws += 3145728;     // 3 planes [c][a][k]
    float* RBF    = ws; ws += 5242880;     // sorted
    float* UNITFC = ws; ws += 1048576;     // sorted
    ushort* PHIB  = (ushort*)ws; ws += 1572864;   // 8192*384
    ushort* VBFA  = (ushort*)ws; ws += 1572864;   // v bf16 planes (gather)
    ushort* VBFB  = (ushort*)ws; ws += 1572864;   // post-agg v bf16 planes (GEMM A)
    ushort* SBF   = (ushort*)ws; ws += 524288;
    ushort* WT    = (ushort*)ws; ws += 278528;
    int* CNT  = (int*)ws;
    int* OFF  = CNT + 8192;
    int* CUR  = OFF + 8193;
    int* SRCS = CUR + 8192;

    hipMemsetAsync(CNT, 0, 8192 * sizeof(int), stream);
    hipMemsetAsync(d_out, 0, N_MOL * sizeof(float), stream);

    k_wconv<<<2176, 256, 0, stream>>>(msg_w1, msg_w2, upd_u, upd_v, upd_a1, upd_a2, out_w1, WT);
    k_embed<<<4096, 256, 0, stream>>>(z, embed, S, SBF);
    k_hist<<<1024, 256, 0, stream>>>(edst, CNT);
    k_scan<<<1, 1024, 0, stream>>>(CNT, OFF, CUR);
    k_edges<<<1024, 256, 0, stream>>>(pos, esrc, edst, CUR, RBF, UNITFC, SRCS);

    for (int l = 0; l < LLAYERS; l++) {
        const ushort* W1T = WT + l*16384;
        const ushort* W2T = WT + 49152  + l*49152;
        const ushort* UVT = WT + 196608 + l*32768;
        const ushort* A1T = WT + 294912 + l*32768;
        const ushort* A2T = WT + 393216 + l*49152;

        k_msg<<<512, 256, 0, stream>>>(SBF, W1T, msg_b1 + (size_t)l*128,
                                       W2T, msg_b2 + (size_t)l*384, PHIB);
        if (l == 0)
            k_aggregate<true><<<2048, 192, 0, stream>>>(PHIB, VBFA, S, SBF, V, VBFB,
                RBF, UNITFC, SRCS, OFF, rbf_w + (size_t)l*20*384, rbf_b + (size_t)l*384);
        else
            k_aggregate<false><<<2048, 192, 0, stream>>>(PHIB, VBFA, S, SBF, V, VBFB,
                RBF, UNITFC, SRCS, OFF, rbf_w + (size_t)l*20*384, rbf_b + (size_t)l*384);
        k_upd<<<512, 256, 0, stream>>>(VBFB, UVT, SBF, A1T, upd_a1b + (size_t)l*128,
            A2T, upd_a2b + (size_t)l*384, S, SBF, V, VBFA);
    }

    k_readout<<<512, 64, 0, stream>>>(SBF, WT + 540672, out_b1, out_w2, out_b2,
                                      mol, (float*)d_out);
}

// Round 12
// 603.145 us; speedup vs baseline: 1.1677x; 1.0857x over previous
//
#include <hip/hip_runtime.h>
#include <hip/hip_bf16.h>
#include <math.h>

#define N_ATOMS 8192
#define N_EDGES 262144
#define N_MOL   128
#define FDIM    128
#define RDIM    20
#define LLAYERS 3
#define CUTOFF  5.0f
#define EPSV    1e-8f
#define PI_F    3.14159265358979323846f

typedef __attribute__((ext_vector_type(8))) short bf16x8;
typedef __attribute__((ext_vector_type(4))) float f32x4;

#define VPLANE 1048576   // 8192*128 elements per component plane

__device__ __forceinline__ ushort f2bf(float x) {
    uint b = __float_as_uint(x);
    return (ushort)((b + 0x7fffu + ((b >> 16) & 1u)) >> 16);
}

// ---------------- weight convert+transpose (f32 KxN -> bf16 NxK) ----------------
__global__ void k_wconv(const float* __restrict__ w1, const float* __restrict__ w2,
                        const float* __restrict__ uu, const float* __restrict__ uvw,
                        const float* __restrict__ a1, const float* __restrict__ a2,
                        const float* __restrict__ ow1, ushort* __restrict__ WT) {
    int i = blockIdx.x * 256 + threadIdx.x;  // < 557056
    float v;
    if (i < 49152) {                          // W1T
        int idx = i; int l = idx >> 14; idx &= 16383;
        int n = idx >> 7, k = idx & 127;
        v = w1[l*16384 + k*128 + n];
    } else if (i < 196608) {                  // W2T
        int idx = i - 49152; int l = idx / 49152; idx -= l * 49152;
        int n = idx >> 7, k = idx & 127;
        v = w2[l*49152 + k*384 + n];
    } else if (i < 294912) {                  // UVT (u cols 0-127, v cols 128-255)
        int idx = i - 196608; int l = idx >> 15; idx &= 32767;
        int n = idx >> 7, k = idx & 127;
        v = (n < 128) ? uu[l*16384 + k*128 + n] : uvw[l*16384 + k*128 + (n-128)];
    } else if (i < 393216) {                  // A1T (128n x 256k)
        int idx = i - 294912; int l = idx >> 15; idx &= 32767;
        int n = idx >> 8, k = idx & 255;
        v = a1[l*32768 + k*128 + n];
    } else if (i < 540672) {                  // A2T
        int idx = i - 393216; int l = idx / 49152; idx -= l * 49152;
        int n = idx >> 7, k = idx & 127;
        v = a2[l*49152 + k*384 + n];
    } else {                                  // OW1T
        int idx = i - 540672;
        int n = idx >> 7, k = idx & 127;
        v = ow1[k*128 + n];
    }
    WT[i] = f2bf(v);
}

// ---------------- embed gather ----------------
__global__ void k_embed(const int* __restrict__ z, const float* __restrict__ embed,
                        float* __restrict__ S, ushort* __restrict__ SBF) {
    int i = blockIdx.x * 256 + threadIdx.x;
    int a = i >> 7, k = i & 127;
    float v = embed[(size_t)z[a] * FDIM + k];
    S[i] = v; SBF[i] = f2bf(v);
}

// ---------------- CSR build ----------------
__global__ void k_hist(const int* __restrict__ edst, int* __restrict__ CNT) {
    int e = blockIdx.x * 256 + threadIdx.x;
    if (e < N_EDGES) atomicAdd(&CNT[edst[e]], 1);
}

__global__ __launch_bounds__(1024) void k_scan(const int* __restrict__ CNT,
                                               int* __restrict__ OFF, int* __restrict__ CUR) {
    __shared__ int part[1024];
    int t = threadIdx.x;
    int loc[8];
    int run = 0;
    #pragma unroll
    for (int i = 0; i < 8; i++) { int c = CNT[t*8 + i]; loc[i] = run; run += c; }
    part[t] = run;
    __syncthreads();
    for (int off = 1; off < 1024; off <<= 1) {
        int v = 0;
        if (t >= off) v = part[t - off];
        __syncthreads();
        part[t] += v;
        __syncthreads();
    }
    int ebase = (t > 0) ? part[t-1] : 0;
    #pragma unroll
    for (int i = 0; i < 8; i++) { int o = ebase + loc[i]; OFF[t*8+i] = o; CUR[t*8+i] = o; }
    if (t == 1023) OFF[8192] = part[1023];
}

// ---------------- edge geometry, CSR-sorted: UNITFC = (ux,uy,uz,d); rbf on-the-fly later ----------------
__global__ void k_edges(const float* __restrict__ pos, const int* __restrict__ esrc,
                        const int* __restrict__ edst, int* __restrict__ CUR,
                        float* __restrict__ UNITFC, int* __restrict__ SRCS) {
    int e = blockIdx.x * 256 + threadIdx.x;
    if (e >= N_EDGES) return;
    int s = esrc[e], d = edst[e];
    int p = atomicAdd(&CUR[d], 1);
    float rx = pos[d*3+0] - pos[s*3+0];
    float ry = pos[d*3+1] - pos[s*3+1];
    float rz = pos[d*3+2] - pos[s*3+2];
    float dd = sqrtf(rx*rx + ry*ry + rz*rz + EPSV);
    float inv = 1.0f / dd;
    float4 u4; u4.x = rx*inv; u4.y = ry*inv; u4.z = rz*inv; u4.w = dd;
    *(float4*)&UNITFC[(size_t)p*4] = u4;
    SRCS[p] = s;
}

// ---------------- fused message MLP (4 waves): PHIB = (silu(S@w1+b1))@w2+b2 ----------------
__global__ __launch_bounds__(256) void k_msg(
    const ushort* __restrict__ SBF, const ushort* __restrict__ W1T, const float* __restrict__ b1,
    const ushort* __restrict__ W2T, const float* __restrict__ b2, ushort* __restrict__ PHIB)
{
    int tid = threadIdx.x;
    int w = tid >> 6, l = tid & 63;
    int bm = blockIdx.x * 16;
    int lrow = l & 15, lk = (l >> 4) * 8;
    __shared__ ushort Hs[16][136];

    f32x4 acc[2] = {{0.f,0.f,0.f,0.f},{0.f,0.f,0.f,0.f}};
    #pragma unroll
    for (int k0 = 0; k0 < 128; k0 += 32) {
        bf16x8 af = *(const bf16x8*)&SBF[(size_t)(bm + lrow)*128 + k0 + lk];
        #pragma unroll
        for (int t = 0; t < 2; t++) {
            int n = (2*w + t)*16 + lrow;
            bf16x8 bf = *(const bf16x8*)&W1T[(size_t)n*128 + k0 + lk];
            acc[t] = __builtin_amdgcn_mfma_f32_16x16x32_bf16(af, bf, acc[t], 0, 0, 0);
        }
    }
    #pragma unroll
    for (int t = 0; t < 2; t++) {
        int col = (2*w + t)*16 + lrow;
        float bv = b1[col];
        #pragma unroll
        for (int j = 0; j < 4; j++) {
            int row = (l >> 4)*4 + j;
            float val = acc[t][j] + bv;
            val = val / (1.0f + __expf(-val));
            Hs[row][col] = f2bf(val);
        }
    }
    __syncthreads();

    f32x4 acc2[6];
    #pragma unroll
    for (int t = 0; t < 6; t++) acc2[t] = (f32x4){0.f,0.f,0.f,0.f};
    #pragma unroll
    for (int k0 = 0; k0 < 128; k0 += 32) {
        bf16x8 af = *(const bf16x8*)&Hs[lrow][k0 + lk];
        #pragma unroll
        for (int t = 0; t < 6; t++) {
            int n = (6*w + t)*16 + lrow;
            bf16x8 bf = *(const bf16x8*)&W2T[(size_t)n*128 + k0 + lk];
            acc2[t] = __builtin_amdgcn_mfma_f32_16x16x32_bf16(af, bf, acc2[t], 0, 0, 0);
        }
    }
    #pragma unroll
    for (int t = 0; t < 6; t++) {
        int col = (6*w + t)*16 + lrow;
        float bv = b2[col];
        #pragma unroll
        for (int j = 0; j < 4; j++) {
            int row = bm + (l >> 4)*4 + j;
            PHIB[(size_t)row*384 + col] = f2bf(acc2[t][j] + bv);
        }
    }
}

// ---------------- edge aggregation: 1 atom/block, depth-2 pipeline, on-the-fly rbf/fc ----------------
template<bool L0>
__global__ __launch_bounds__(192) void k_aggregate(
    const ushort* __restrict__ PHIB, const ushort* __restrict__ VBFA,
    float* __restrict__ S, ushort* __restrict__ SBF,
    float* __restrict__ V, ushort* __restrict__ VBFB,
    const float* __restrict__ UNITFC,
    const int* __restrict__ SRCS, const int* __restrict__ OFF,
    const float* __restrict__ rbfw, const float* __restrict__ rbfb)
{
    int a = blockIdx.x;
    int tid = threadIdx.x;
    int g = tid >> 6;          // wave role: 0=ds, 1=v*dvv, 2=unit*dvs
    int c0 = 2 * (tid & 63);   // channel pair within section

    float2 w[RDIM];
    const float* wc = rbfw + g*128 + c0;
    #pragma unroll
    for (int r = 0; r < RDIM; r++) { w[r].x = wc[r*384]; w[r].y = wc[r*384 + 1]; }
    float2 bb; bb.x = rbfb[g*128 + c0]; bb.y = rbfb[g*128 + c0 + 1];

    __shared__ int sSrc[64];
    __shared__ float4 sRBF[320];
    __shared__ float4 sUFC[64];
    __shared__ float avs[3][128];
    float* sRBFf = (float*)sRBF;

    int beg = OFF[a], end = OFF[a + 1];
    float2 d; d.x = 0.f; d.y = 0.f;
    float2 A0, A1, A2v;
    A0.x=A0.y=A1.x=A1.y=A2v.x=A2v.y=0.f;

    for (int p0 = beg; p0 < end; p0 += 64) {
        int n = end - p0; if (n > 64) n = 64;
        __syncthreads();
        if (tid < n) {
            sSrc[tid] = SRCS[p0 + tid];
            float4 u4 = *(const float4*)(UNITFC + (size_t)(p0 + tid) * 4);
            float dd = u4.w;
            u4.w = (dd < CUTOFF) ? 0.5f * (__cosf(dd * (PI_F / CUTOFF)) + 1.0f) : 0.0f;
            sUFC[tid] = u4;
        }
        for (int i = tid; i < n * RDIM; i += 192) {
            int e = i / RDIM, r = i - e * RDIM;
            float dd = UNITFC[(size_t)(p0 + e) * 4 + 3];
            sRBFf[i] = __sinf(dd * (float)(r + 1) * (PI_F / CUTOFF)) / dd;
        }
        __syncthreads();

        if (L0 && g == 1) continue;   // layer 0: v == 0, g1 contributes nothing

        uint phA[4], u0A[4], u1A[4], u2A[4];
        uint phB[4], u0B[4], u1B[4], u2B[4];

        auto grpLoad = [&](int base, uint* ph, uint* u0, uint* u1, uint* u2) {
            #pragma unroll
            for (int j = 0; j < 4; j++) {
                int q = base + j;
                int src = sSrc[(q < n) ? q : 0];
                size_t pb = (size_t)src * 128;
                ph[j] = *(const uint*)&PHIB[(size_t)src*384 + g*128 + c0];
                if (!L0 && g == 1) {
                    u0[j] = *(const uint*)&VBFA[pb + c0];
                    u1[j] = *(const uint*)&VBFA[pb + VPLANE + c0];
                    u2[j] = *(const uint*)&VBFA[pb + 2*VPLANE + c0];
                }
            }
        };
        grpLoad(0, phA, u0A, u1A, u2A);
        for (int q0 = 0; q0 < n; q0 += 4) {
            if (q0 + 4 < n) grpLoad(q0 + 4, phB, u0B, u1B, u2B);
            #pragma unroll
            for (int j = 0; j < 4; j++) {
                int q = q0 + j;
                if (q >= n) break;
                float4 r0 = sRBF[q*5+0], r1 = sRBF[q*5+1], r2 = sRBF[q*5+2],
                       r3 = sRBF[q*5+3], r4 = sRBF[q*5+4];
                float4 ufc = sUFC[q];
                float2 f = bb;
                f.x += r0.x*w[0].x;   f.y += r0.x*w[0].y;
                f.x += r0.y*w[1].x;   f.y += r0.y*w[1].y;
                f.x += r0.z*w[2].x;   f.y += r0.z*w[2].y;
                f.x += r0.w*w[3].x;   f.y += r0.w*w[3].y;
                f.x += r1.x*w[4].x;   f.y += r1.x*w[4].y;
                f.x += r1.y*w[5].x;   f.y += r1.y*w[5].y;
                f.x += r1.z*w[6].x;   f.y += r1.z*w[6].y;
                f.x += r1.w*w[7].x;   f.y += r1.w*w[7].y;
                f.x += r2.x*w[8].x;   f.y += r2.x*w[8].y;
                f.x += r2.y*w[9].x;   f.y += r2.y*w[9].y;
                f.x += r2.z*w[10].x;  f.y += r2.z*w[10].y;
                f.x += r2.w*w[11].x;  f.y += r2.w*w[11].y;
                f.x += r3.x*w[12].x;  f.y += r3.x*w[12].y;
                f.x += r3.y*w[13].x;  f.y += r3.y*w[13].y;
                f.x += r3.z*w[14].x;  f.y += r3.z*w[14].y;
                f.x += r3.w*w[15].x;  f.y += r3.w*w[15].y;
                f.x += r4.x*w[16].x;  f.y += r4.x*w[16].y;
                f.x += r4.y*w[17].x;  f.y += r4.y*w[17].y;
                f.x += r4.z*w[18].x;  f.y += r4.z*w[18].y;
                f.x += r4.w*w[19].x;  f.y += r4.w*w[19].y;
                uint up = phA[j];
                float m0 = __uint_as_float(up << 16)         * (f.x * ufc.w);
                float m1 = __uint_as_float(up & 0xffff0000u) * (f.y * ufc.w);
                if (g == 0) {
                    d.x += m0; d.y += m1;
                } else if (g == 1) {
                    A0.x  += __uint_as_float(u0A[j] << 16)         * m0;
                    A0.y  += __uint_as_float(u0A[j] & 0xffff0000u) * m1;
                    A1.x  += __uint_as_float(u1A[j] << 16)         * m0;
                    A1.y  += __uint_as_float(u1A[j] & 0xffff0000u) * m1;
                    A2v.x += __uint_as_float(u2A[j] << 16)         * m0;
                    A2v.y += __uint_as_float(u2A[j] & 0xffff0000u) * m1;
                } else {
                    A0.x  += ufc.x * m0; A0.y  += ufc.x * m1;
                    A1.x  += ufc.y * m0; A1.y  += ufc.y * m1;
                    A2v.x += ufc.z * m0; A2v.y += ufc.z * m1;
                }
            }
            #pragma unroll
            for (int j = 0; j < 4; j++) {
                phA[j] = phB[j]; u0A[j] = u0B[j]; u1A[j] = u1B[j]; u2A[j] = u2B[j];
            }
        }
    }

    if (g == 1) {
        avs[0][c0] = A0.x;  avs[0][c0+1] = A0.y;
        avs[1][c0] = A1.x;  avs[1][c0+1] = A1.y;
        avs[2][c0] = A2v.x; avs[2][c0+1] = A2v.y;
    }
    __syncthreads();
    if (g == 0) {
        size_t sb = (size_t)a*128 + c0;
        float2 s2 = *(float2*)&S[sb];
        s2.x += d.x; s2.y += d.y;
        *(float2*)&S[sb] = s2;
        SBF[sb] = f2bf(s2.x); SBF[sb+1] = f2bf(s2.y);
    } else if (g == 2) {
        float own0[3] = {A0.x, A1.x, A2v.x};
        float own1[3] = {A0.y, A1.y, A2v.y};
        #pragma unroll
        for (int c = 0; c < 3; c++) {
            size_t vb = (size_t)c*VPLANE + (size_t)a*128 + c0;
            float2 vi;
            if (L0) { vi.x = 0.f; vi.y = 0.f; }
            else    vi = *(const float2*)&V[vb];
            vi.x += avs[c][c0]     + own0[c];
            vi.y += avs[c][c0 + 1] + own1[c];
            *(float2*)&V[vb] = vi;
            VBFB[vb] = f2bf(vi.x); VBFB[vb+1] = f2bf(vi.y);
        }
    }
}

// ---------------- fused update: uv/vv GEMM + vvdot + a-MLP + s/v update ----------------
__global__ __launch_bounds__(256) void k_upd(
    const ushort* __restrict__ VBFB, const ushort* __restrict__ UVT,
    const ushort* __restrict__ SBF_in,
    const ushort* __restrict__ A1T, const float* __restrict__ a1b,
    const ushort* __restrict__ A2T, const float* __restrict__ a2b,
    float* __restrict__ S, ushort* __restrict__ SBF,
    float* __restrict__ V, ushort* __restrict__ VBFA)
{
    int tid = threadIdx.x;
    int w = tid >> 6, l = tid & 63;
    int bm = blockIdx.x * 16;
    int lrow = l & 15, lk = (l >> 4) * 8;
    __shared__ ushort sVVN[16][136];
    __shared__ ushort Hs[16][136];

    f32x4 au[3][2], av[3][2];
    #pragma unroll
    for (int c = 0; c < 3; c++)
        #pragma unroll
        for (int t = 0; t < 2; t++) {
            au[c][t] = (f32x4){0.f,0.f,0.f,0.f};
            av[c][t] = (f32x4){0.f,0.f,0.f,0.f};
        }
    #pragma unroll
    for (int k0 = 0; k0 < 128; k0 += 32) {
        bf16x8 af[3];
        #pragma unroll
        for (int c = 0; c < 3; c++)
            af[c] = *(const bf16x8*)&VBFB[(size_t)c*VPLANE + (size_t)(bm + lrow)*128 + k0 + lk];
        #pragma unroll
        for (int t = 0; t < 2; t++) {
            int nu = (2*w + t)*16 + lrow;
            bf16x8 bu = *(const bf16x8*)&UVT[(size_t)nu*128 + k0 + lk];
            bf16x8 bv = *(const bf16x8*)&UVT[(size_t)(nu + 128)*128 + k0 + lk];
            #pragma unroll
            for (int c = 0; c < 3; c++) {
                au[c][t] = __builtin_amdgcn_mfma_f32_16x16x32_bf16(af[c], bu, au[c][t], 0, 0, 0);
                av[c][t] = __builtin_amdgcn_mfma_f32_16x16x32_bf16(af[c], bv, av[c][t], 0, 0, 0);
            }
        }
    }
    float dotr[2][4], uvr[3][2][4];
    #pragma unroll
    for (int t = 0; t < 2; t++) {
        int k = (2*w + t)*16 + lrow;
        #pragma unroll
        for (int j = 0; j < 4; j++) {
            int row = (l >> 4)*4 + j;
            float u0 = au[0][t][j], u1 = au[1][t][j], u2 = au[2][t][j];
            float v0 = av[0][t][j], v1 = av[1][t][j], v2 = av[2][t][j];
            uvr[0][t][j] = u0; uvr[1][t][j] = u1; uvr[2][t][j] = u2;
            dotr[t][j] = u0*v0 + u1*v1 + u2*v2;
            sVVN[row][k] = f2bf(sqrtf(v0*v0 + v1*v1 + v2*v2 + EPSV));
        }
    }
    __syncthreads();

    f32x4 acc[2] = {{0.f,0.f,0.f,0.f},{0.f,0.f,0.f,0.f}};
    #pragma unroll
    for (int k0 = 0; k0 < 256; k0 += 32) {
        bf16x8 af;
        if (k0 < 128) af = *(const bf16x8*)&SBF_in[(size_t)(bm + lrow)*128 + k0 + lk];
        else          af = *(const bf16x8*)&sVVN[lrow][k0 + lk - 128];
        #pragma unroll
        for (int t = 0; t < 2; t++) {
            int n = (2*w + t)*16 + lrow;
            bf16x8 bf = *(const bf16x8*)&A1T[(size_t)n*256 + k0 + lk];
            acc[t] = __builtin_amdgcn_mfma_f32_16x16x32_bf16(af, bf, acc[t], 0, 0, 0);
        }
    }
    #pragma unroll
    for (int t = 0; t < 2; t++) {
        int col = (2*w + t)*16 + lrow;
        float bv = a1b[col];
        #pragma unroll
        for (int j = 0; j < 4; j++) {
            int row = (l >> 4)*4 + j;
            float val = acc[t][j] + bv;
            val = val / (1.0f + __expf(-val));
            Hs[row][col] = f2bf(val);
        }
    }
    __syncthreads();

    f32x4 c_vv[2], c_sv[2], c_ss[2];
    #pragma unroll
    for (int t = 0; t < 2; t++) {
        c_vv[t] = (f32x4){0.f,0.f,0.f,0.f};
        c_sv[t] = (f32x4){0.f,0.f,0.f,0.f};
        c_ss[t] = (f32x4){0.f,0.f,0.f,0.f};
    }
    #pragma unroll
    for (int k0 = 0; k0 < 128; k0 += 32) {
        bf16x8 af = *(const bf16x8*)&Hs[lrow][k0 + lk];
        #pragma unroll
        for (int t = 0; t < 2; t++) {
            int n0 = (2*w + t)*16 + lrow;
            bf16x8 b0 = *(const bf16x8*)&A2T[(size_t)n0*128 + k0 + lk];
            bf16x8 b1 = *(const bf16x8*)&A2T[(size_t)(n0 + 128)*128 + k0 + lk];
            bf16x8 b2 = *(const bf16x8*)&A2T[(size_t)(n0 + 256)*128 + k0 + lk];
            c_vv[t] = __builtin_amdgcn_mfma_f32_16x16x32_bf16(af, b0, c_vv[t], 0, 0, 0);
            c_sv[t] = __builtin_amdgcn_mfma_f32_16x16x32_bf16(af, b1, c_sv[t], 0, 0, 0);
            c_ss[t] = __builtin_amdgcn_mfma_f32_16x16x32_bf16(af, b2, c_ss[t], 0, 0, 0);
        }
    }
    #pragma unroll
    for (int t = 0; t < 2; t++) {
        int k = (2*w + t)*16 + lrow;
        float b_vv = a2b[k], b_sv = a2b[128 + k], b_ss = a2b[256 + k];
        #pragma unroll
        for (int j = 0; j < 4; j++) {
            int a = bm + (l >> 4)*4 + j;
            size_t base = (size_t)a*128 + k;
            float vv = c_vv[t][j] + b_vv;
            float sv = c_sv[t][j] + b_sv;
            float ss = c_ss[t][j] + b_ss;
            float sn = S[base] + ss + sv * dotr[t][j];
            S[base] = sn; SBF[base] = f2bf(sn);
            #pragma unroll
            for (int c = 0; c < 3; c++) {
                size_t vb = (size_t)c*VPLANE + base;
                float nv = V[vb] + vv * uvr[c][t][j];
                V[vb] = nv; VBFA[vb] = f2bf(nv);
            }
        }
    }
}

// ---------------- fused readout + molecule accumulation ----------------
__global__ __launch_bounds__(64) void k_readout(
    const ushort* __restrict__ SBF, const ushort* __restrict__ OW1T,
    const float* __restrict__ b1, const float* __restrict__ w2,
    const float* __restrict__ b2v, const int* __restrict__ mol,
    float* __restrict__ out)
{
    int l = threadIdx.x;
    int bm = blockIdx.x * 16;
    int lrow = l & 15, lk = (l >> 4) * 8;
    __shared__ float Hs[16][132];

    f32x4 acc[8];
    #pragma unroll
    for (int t = 0; t < 8; t++) acc[t] = (f32x4){0.f,0.f,0.f,0.f};
    #pragma unroll
    for (int k0 = 0; k0 < 128; k0 += 32) {
        bf16x8 af = *(const bf16x8*)&SBF[(size_t)(bm + lrow)*128 + k0 + lk];
        #pragma unroll
        for (int t = 0; t < 8; t++) {
            bf16x8 bf = *(const bf16x8*)&OW1T[(size_t)(t*16 + lrow)*128 + k0 + lk];
            acc[t] = __builtin_amdgcn_mfma_f32_16x16x32_bf16(af, bf, acc[t], 0, 0, 0);
        }
    }
    #pragma unroll
    for (int t = 0; t < 8; t++) {
        int col = t*16 + lrow;
        float bv = b1[col];
        #pragma unroll
        for (int j = 0; j < 4; j++) {
            int row = (l >> 4)*4 + j;
            float val = acc[t][j] + bv;
            Hs[row][col] = val / (1.0f + __expf(-val));
        }
    }
    __syncthreads();
    if (l < 16) {
        float s = b2v[0];
        #pragma unroll 8
        for (int k = 0; k < 128; k++) s += Hs[l][k] * w2[k];
        atomicAdd(&out[mol[bm + l]], s);
    }
}

extern "C" void kernel_launch(void* const* d_in, const int* in_sizes, int n_in,
                              void* d_out, int out_size, void* d_ws, size_t ws_size,
                              hipStream_t stream) {
    const int*   z      = (const int*)d_in[0];
    const float* pos    = (const float*)d_in[1];
    const int*   esrc   = (const int*)d_in[2];
    const int*   edst   = (const int*)d_in[3];
    const int*   mol    = (const int*)d_in[4];
    const float* embed  = (const float*)d_in[5];
    const float* msg_w1 = (const float*)d_in[6];
    const float* msg_b1 = (const float*)d_in[7];
    const float* msg_w2 = (const float*)d_in[8];
    const float* msg_b2 = (const float*)d_in[9];
    const float* rbf_w  = (const float*)d_in[10];
    const float* rbf_b  = (const float*)d_in[11];
    const float* upd_u  = (const float*)d_in[12];
    const float* upd_v  = (const float*)d_in[13];
    const float* upd_a1 = (const float*)d_in[14];
    const float* upd_a1b= (const float*)d_in[15];
    const float* upd_a2 = (const float*)d_in[16];
    const float* upd_a2b= (const float*)d_in[17];
    const float* out_w1 = (const float*)d_in[18];
    const float* out_b1 = (const float*)d_in[19];
    const float* out_w2 = (const float*)d_in[20];
    const float* out_b2 = (const float*)d_in[21];

    float* ws = (float*)d_ws;
    float* S      = ws; ws += 1048576;     // 8192*128 f32
    float* V      = ws; ws += 3145728;     // 3 planes [c][a][k]
    float* UNITFC = ws; ws += 1048576;     // sorted (ux,uy,uz,d)
    ushort* PHIB  = (ushort*)ws; ws += 1572864;   // 8192*384
    ushort* VBFA  = (ushort*)ws; ws += 1572864;   // v bf16 planes (gather)
    ushort* VBFB  = (ushort*)ws; ws += 1572864;   // post-agg v bf16 planes (GEMM A)
    ushort* SBF   = (ushort*)ws; ws += 524288;
    ushort* WT    = (ushort*)ws; ws += 278528;
    int* CNT  = (int*)ws;
    int* OFF  = CNT + 8192;
    int* CUR  = OFF + 8193;
    int* SRCS = CUR + 8192;

    hipMemsetAsync(CNT, 0, 8192 * sizeof(int), stream);
    hipMemsetAsync(d_out, 0, N_MOL * sizeof(float), stream);

    k_wconv<<<2176, 256, 0, stream>>>(msg_w1, msg_w2, upd_u, upd_v, upd_a1, upd_a2, out_w1, WT);
    k_embed<<<4096, 256, 0, stream>>>(z, embed, S, SBF);
    k_hist<<<1024, 256, 0, stream>>>(edst, CNT);
    k_scan<<<1, 1024, 0, stream>>>(CNT, OFF, CUR);
    k_edges<<<1024, 256, 0, stream>>>(pos, esrc, edst, CUR, UNITFC, SRCS);

    for (int l = 0; l < LLAYERS; l++) {
        const ushort* W1T = WT + l*16384;
        const ushort* W2T = WT + 49152  + l*49152;
        const ushort* UVT = WT + 196608 + l*32768;
        const ushort* A1T = WT + 294912 + l*32768;
        const ushort* A2T = WT + 393216 + l*49152;

        k_msg<<<512, 256, 0, stream>>>(SBF, W1T, msg_b1 + (size_t)l*128,
                                       W2T, msg_b2 + (size_t)l*384, PHIB);
        if (l == 0)
            k_aggregate<true><<<8192, 192, 0, stream>>>(PHIB, VBFA, S, SBF, V, VBFB,
                UNITFC, SRCS, OFF, rbf_w + (size_t)l*20*384, rbf_b + (size_t)l*384);
        else
            k_aggregate<false><<<8192, 192, 0, stream>>>(PHIB, VBFA, S, SBF, V, VBFB,
                UNITFC, SRCS, OFF, rbf_w + (size_t)l*20*384, rbf_b + (size_t)l*384);
        k_upd<<<512, 256, 0, stream>>>(VBFB, UVT, SBF, A1T, upd_a1b + (size_t)l*128,
            A2T, upd_a2b + (size_t)l*384, S, SBF, V, VBFA);
    }

    k_readout<<<512, 64, 0, stream>>>(SBF, WT + 540672, out_b1, out_w2, out_b2,
                                      mol, (float*)d_out);
}

// Round 13
// 586.490 us; speedup vs baseline: 1.2009x; 1.0284x over previous
//
#include <hip/hip_runtime.h>
#include <hip/hip_bf16.h>
#include <math.h>

#define N_ATOMS 8192
#define N_EDGES 262144
#define N_MOL   128
#define FDIM    128
#define RDIM    20
#define LLAYERS 3
#define CUTOFF  5.0f
#define EPSV    1e-8f
#define PI_F    3.14159265358979323846f

typedef __attribute__((ext_vector_type(8))) short bf16x8;
typedef __attribute__((ext_vector_type(4))) float f32x4;

#define VPLANE 1048576   // 8192*128 elements per component plane

__device__ __forceinline__ ushort f2bf(float x) {
    uint b = __float_as_uint(x);
    return (ushort)((b + 0x7fffu + ((b >> 16) & 1u)) >> 16);
}

// ---------------- weight convert+transpose (f32 KxN -> bf16 NxK) ----------------
__global__ void k_wconv(const float* __restrict__ w1, const float* __restrict__ w2,
                        const float* __restrict__ uu, const float* __restrict__ uvw,
                        const float* __restrict__ a1, const float* __restrict__ a2,
                        const float* __restrict__ ow1, ushort* __restrict__ WT) {
    int i = blockIdx.x * 256 + threadIdx.x;  // < 557056
    float v;
    if (i < 49152) {                          // W1T
        int idx = i; int l = idx >> 14; idx &= 16383;
        int n = idx >> 7, k = idx & 127;
        v = w1[l*16384 + k*128 + n];
    } else if (i < 196608) {                  // W2T
        int idx = i - 49152; int l = idx / 49152; idx -= l * 49152;
        int n = idx >> 7, k = idx & 127;
        v = w2[l*49152 + k*384 + n];
    } else if (i < 294912) {                  // UVT (u cols 0-127, v cols 128-255)
        int idx = i - 196608; int l = idx >> 15; idx &= 32767;
        int n = idx >> 7, k = idx & 127;
        v = (n < 128) ? uu[l*16384 + k*128 + n] : uvw[l*16384 + k*128 + (n-128)];
    } else if (i < 393216) {                  // A1T (128n x 256k)
        int idx = i - 294912; int l = idx >> 15; idx &= 32767;
        int n = idx >> 8, k = idx & 255;
        v = a1[l*32768 + k*128 + n];
    } else if (i < 540672) {                  // A2T
        int idx = i - 393216; int l = idx / 49152; idx -= l * 49152;
        int n = idx >> 7, k = idx & 127;
        v = a2[l*49152 + k*384 + n];
    } else {                                  // OW1T
        int idx = i - 540672;
        int n = idx >> 7, k = idx & 127;
        v = ow1[k*128 + n];
    }
    WT[i] = f2bf(v);
}

// ---------------- embed gather ----------------
__global__ void k_embed(const int* __restrict__ z, const float* __restrict__ embed,
                        float* __restrict__ S, ushort* __restrict__ SBF) {
    int i = blockIdx.x * 256 + threadIdx.x;
    int a = i >> 7, k = i & 127;
    float v = embed[(size_t)z[a] * FDIM + k];
    S[i] = v; SBF[i] = f2bf(v);
}

// ---------------- CSR build ----------------
__global__ void k_hist(const int* __restrict__ edst, int* __restrict__ CNT) {
    int e = blockIdx.x * 256 + threadIdx.x;
    if (e < N_EDGES) atomicAdd(&CNT[edst[e]], 1);
}

__global__ __launch_bounds__(1024) void k_scan(const int* __restrict__ CNT,
                                               int* __restrict__ OFF, int* __restrict__ CUR) {
    __shared__ int part[1024];
    int t = threadIdx.x;
    int loc[8];
    int run = 0;
    #pragma unroll
    for (int i = 0; i < 8; i++) { int c = CNT[t*8 + i]; loc[i] = run; run += c; }
    part[t] = run;
    __syncthreads();
    for (int off = 1; off < 1024; off <<= 1) {
        int v = 0;
        if (t >= off) v = part[t - off];
        __syncthreads();
        part[t] += v;
        __syncthreads();
    }
    int ebase = (t > 0) ? part[t-1] : 0;
    #pragma unroll
    for (int i = 0; i < 8; i++) { int o = ebase + loc[i]; OFF[t*8+i] = o; CUR[t*8+i] = o; }
    if (t == 1023) OFF[8192] = part[1023];
}

// ---------------- edge geometry, CSR-sorted: UNITFC = (ux,uy,uz,d) ----------------
__global__ void k_edges(const float* __restrict__ pos, const int* __restrict__ esrc,
                        const int* __restrict__ edst, int* __restrict__ CUR,
                        float* __restrict__ UNITFC, int* __restrict__ SRCS) {
    int e = blockIdx.x * 256 + threadIdx.x;
    if (e >= N_EDGES) return;
    int s = esrc[e], d = edst[e];
    int p = atomicAdd(&CUR[d], 1);
    float rx = pos[d*3+0] - pos[s*3+0];
    float ry = pos[d*3+1] - pos[s*3+1];
    float rz = pos[d*3+2] - pos[s*3+2];
    float dd = sqrtf(rx*rx + ry*ry + rz*rz + EPSV);
    float inv = 1.0f / dd;
    float4 u4; u4.x = rx*inv; u4.y = ry*inv; u4.z = rz*inv; u4.w = dd;
    *(float4*)&UNITFC[(size_t)p*4] = u4;
    SRCS[p] = s;
}

// ---------------- standalone message MLP (layer 0 only) ----------------
__global__ __launch_bounds__(256) void k_msg(
    const ushort* __restrict__ SBF, const ushort* __restrict__ W1T, const float* __restrict__ b1,
    const ushort* __restrict__ W2T, const float* __restrict__ b2, ushort* __restrict__ PHIB)
{
    int tid = threadIdx.x;
    int w = tid >> 6, l = tid & 63;
    int bm = blockIdx.x * 16;
    int lrow = l & 15, lk = (l >> 4) * 8;
    __shared__ ushort Hs[16][136];

    f32x4 acc[2] = {{0.f,0.f,0.f,0.f},{0.f,0.f,0.f,0.f}};
    #pragma unroll
    for (int k0 = 0; k0 < 128; k0 += 32) {
        bf16x8 af = *(const bf16x8*)&SBF[(size_t)(bm + lrow)*128 + k0 + lk];
        #pragma unroll
        for (int t = 0; t < 2; t++) {
            int n = (2*w + t)*16 + lrow;
            bf16x8 bf = *(const bf16x8*)&W1T[(size_t)n*128 + k0 + lk];
            acc[t] = __builtin_amdgcn_mfma_f32_16x16x32_bf16(af, bf, acc[t], 0, 0, 0);
        }
    }
    #pragma unroll
    for (int t = 0; t < 2; t++) {
        int col = (2*w + t)*16 + lrow;
        float bv = b1[col];
        #pragma unroll
        for (int j = 0; j < 4; j++) {
            int row = (l >> 4)*4 + j;
            float val = acc[t][j] + bv;
            val = val / (1.0f + __expf(-val));
            Hs[row][col] = f2bf(val);
        }
    }
    __syncthreads();

    f32x4 acc2[6];
    #pragma unroll
    for (int t = 0; t < 6; t++) acc2[t] = (f32x4){0.f,0.f,0.f,0.f};
    #pragma unroll
    for (int k0 = 0; k0 < 128; k0 += 32) {
        bf16x8 af = *(const bf16x8*)&Hs[lrow][k0 + lk];
        #pragma unroll
        for (int t = 0; t < 6; t++) {
            int n = (6*w + t)*16 + lrow;
            bf16x8 bf = *(const bf16x8*)&W2T[(size_t)n*128 + k0 + lk];
            acc2[t] = __builtin_amdgcn_mfma_f32_16x16x32_bf16(af, bf, acc2[t], 0, 0, 0);
        }
    }
    #pragma unroll
    for (int t = 0; t < 6; t++) {
        int col = (6*w + t)*16 + lrow;
        float bv = b2[col];
        #pragma unroll
        for (int j = 0; j < 4; j++) {
            int row = bm + (l >> 4)*4 + j;
            PHIB[(size_t)row*384 + col] = f2bf(acc2[t][j] + bv);
        }
    }
}

// ---------------- edge aggregation: 1 atom/block, depth-2 pipeline, on-the-fly rbf/fc ----------------
template<bool L0>
__global__ __launch_bounds__(192) void k_aggregate(
    const ushort* __restrict__ PHIB, const ushort* __restrict__ VBFA,
    float* __restrict__ S, ushort* __restrict__ SBF,
    float* __restrict__ V, ushort* __restrict__ VBFB,
    const float* __restrict__ UNITFC,
    const int* __restrict__ SRCS, const int* __restrict__ OFF,
    const float* __restrict__ rbfw, const float* __restrict__ rbfb)
{
    int a = blockIdx.x;
    int tid = threadIdx.x;
    int g = tid >> 6;          // wave role: 0=ds, 1=v*dvv, 2=unit*dvs
    int c0 = 2 * (tid & 63);   // channel pair within section

    float2 w[RDIM];
    const float* wc = rbfw + g*128 + c0;
    #pragma unroll
    for (int r = 0; r < RDIM; r++) { w[r].x = wc[r*384]; w[r].y = wc[r*384 + 1]; }
    float2 bb; bb.x = rbfb[g*128 + c0]; bb.y = rbfb[g*128 + c0 + 1];

    __shared__ int sSrc[64];
    __shared__ float4 sRBF[320];
    __shared__ float4 sUFC[64];
    __shared__ float avs[3][128];
    float* sRBFf = (float*)sRBF;

    int beg = OFF[a], end = OFF[a + 1];
    float2 d; d.x = 0.f; d.y = 0.f;
    float2 A0, A1, A2v;
    A0.x=A0.y=A1.x=A1.y=A2v.x=A2v.y=0.f;

    for (int p0 = beg; p0 < end; p0 += 64) {
        int n = end - p0; if (n > 64) n = 64;
        __syncthreads();
        if (tid < n) {
            sSrc[tid] = SRCS[p0 + tid];
            float4 u4 = *(const float4*)(UNITFC + (size_t)(p0 + tid) * 4);
            float dd = u4.w;
            u4.w = (dd < CUTOFF) ? 0.5f * (__cosf(dd * (PI_F / CUTOFF)) + 1.0f) : 0.0f;
            sUFC[tid] = u4;
        }
        for (int i = tid; i < n * RDIM; i += 192) {
            int e = i / RDIM, r = i - e * RDIM;
            float dd = UNITFC[(size_t)(p0 + e) * 4 + 3];
            sRBFf[i] = __sinf(dd * (float)(r + 1) * (PI_F / CUTOFF)) / dd;
        }
        __syncthreads();

        if (L0 && g == 1) continue;   // layer 0: v == 0, g1 contributes nothing

        uint phA[4], u0A[4], u1A[4], u2A[4];
        uint phB[4], u0B[4], u1B[4], u2B[4];

        auto grpLoad = [&](int base, uint* ph, uint* u0, uint* u1, uint* u2) {
            #pragma unroll
            for (int j = 0; j < 4; j++) {
                int q = base + j;
                int src = sSrc[(q < n) ? q : 0];
                size_t pb = (size_t)src * 128;
                ph[j] = *(const uint*)&PHIB[(size_t)src*384 + g*128 + c0];
                if (!L0 && g == 1) {
                    u0[j] = *(const uint*)&VBFA[pb + c0];
                    u1[j] = *(const uint*)&VBFA[pb + VPLANE + c0];
                    u2[j] = *(const uint*)&VBFA[pb + 2*VPLANE + c0];
                }
            }
        };
        grpLoad(0, phA, u0A, u1A, u2A);
        for (int q0 = 0; q0 < n; q0 += 4) {
            if (q0 + 4 < n) grpLoad(q0 + 4, phB, u0B, u1B, u2B);
            #pragma unroll
            for (int j = 0; j < 4; j++) {
                int q = q0 + j;
                if (q >= n) break;
                float4 r0 = sRBF[q*5+0], r1 = sRBF[q*5+1], r2 = sRBF[q*5+2],
                       r3 = sRBF[q*5+3], r4 = sRBF[q*5+4];
                float4 ufc = sUFC[q];
                float2 f = bb;
                f.x += r0.x*w[0].x;   f.y += r0.x*w[0].y;
                f.x += r0.y*w[1].x;   f.y += r0.y*w[1].y;
                f.x += r0.z*w[2].x;   f.y += r0.z*w[2].y;
                f.x += r0.w*w[3].x;   f.y += r0.w*w[3].y;
                f.x += r1.x*w[4].x;   f.y += r1.x*w[4].y;
                f.x += r1.y*w[5].x;   f.y += r1.y*w[5].y;
                f.x += r1.z*w[6].x;   f.y += r1.z*w[6].y;
                f.x += r1.w*w[7].x;   f.y += r1.w*w[7].y;
                f.x += r2.x*w[8].x;   f.y += r2.x*w[8].y;
                f.x += r2.y*w[9].x;   f.y += r2.y*w[9].y;
                f.x += r2.z*w[10].x;  f.y += r2.z*w[10].y;
                f.x += r2.w*w[11].x;  f.y += r2.w*w[11].y;
                f.x += r3.x*w[12].x;  f.y += r3.x*w[12].y;
                f.x += r3.y*w[13].x;  f.y += r3.y*w[13].y;
                f.x += r3.z*w[14].x;  f.y += r3.z*w[14].y;
                f.x += r3.w*w[15].x;  f.y += r3.w*w[15].y;
                f.x += r4.x*w[16].x;  f.y += r4.x*w[16].y;
                f.x += r4.y*w[17].x;  f.y += r4.y*w[17].y;
                f.x += r4.z*w[18].x;  f.y += r4.z*w[18].y;
                f.x += r4.w*w[19].x;  f.y += r4.w*w[19].y;
                uint up = phA[j];
                float m0 = __uint_as_float(up << 16)         * (f.x * ufc.w);
                float m1 = __uint_as_float(up & 0xffff0000u) * (f.y * ufc.w);
                if (g == 0) {
                    d.x += m0; d.y += m1;
                } else if (g == 1) {
                    A0.x  += __uint_as_float(u0A[j] << 16)         * m0;
                    A0.y  += __uint_as_float(u0A[j] & 0xffff0000u) * m1;
                    A1.x  += __uint_as_float(u1A[j] << 16)         * m0;
                    A1.y  += __uint_as_float(u1A[j] & 0xffff0000u) * m1;
                    A2v.x += __uint_as_float(u2A[j] << 16)         * m0;
                    A2v.y += __uint_as_float(u2A[j] & 0xffff0000u) * m1;
                } else {
                    A0.x  += ufc.x * m0; A0.y  += ufc.x * m1;
                    A1.x  += ufc.y * m0; A1.y  += ufc.y * m1;
                    A2v.x += ufc.z * m0; A2v.y += ufc.z * m1;
                }
            }
            #pragma unroll
            for (int j = 0; j < 4; j++) {
                phA[j] = phB[j]; u0A[j] = u0B[j]; u1A[j] = u1B[j]; u2A[j] = u2B[j];
            }
        }
    }

    if (g == 1) {
        avs[0][c0] = A0.x;  avs[0][c0+1] = A0.y;
        avs[1][c0] = A1.x;  avs[1][c0+1] = A1.y;
        avs[2][c0] = A2v.x; avs[2][c0+1] = A2v.y;
    }
    __syncthreads();
    if (g == 0) {
        size_t sb = (size_t)a*128 + c0;
        float2 s2 = *(float2*)&S[sb];
        s2.x += d.x; s2.y += d.y;
        *(float2*)&S[sb] = s2;
        SBF[sb] = f2bf(s2.x); SBF[sb+1] = f2bf(s2.y);
    } else if (g == 2) {
        float own0[3] = {A0.x, A1.x, A2v.x};
        float own1[3] = {A0.y, A1.y, A2v.y};
        #pragma unroll
        for (int c = 0; c < 3; c++) {
            size_t vb = (size_t)c*VPLANE + (size_t)a*128 + c0;
            float2 vi;
            if (L0) { vi.x = 0.f; vi.y = 0.f; }
            else    vi = *(const float2*)&V[vb];
            vi.x += avs[c][c0]     + own0[c];
            vi.y += avs[c][c0 + 1] + own1[c];
            *(float2*)&V[vb] = vi;
            VBFB[vb] = f2bf(vi.x); VBFB[vb+1] = f2bf(vi.y);
        }
    }
}

// ---------------- fused update: uv/vv GEMM + vvdot + a-MLP + s/v update (+ next-layer msg MLP) ----------------
template<bool FUSE_MSG, bool LAST>
__global__ __launch_bounds__(256) void k_upd(
    const ushort* __restrict__ VBFB, const ushort* __restrict__ UVT,
    const ushort* __restrict__ SBF_in,
    const ushort* __restrict__ A1T, const float* __restrict__ a1b,
    const ushort* __restrict__ A2T, const float* __restrict__ a2b,
    float* __restrict__ S, ushort* __restrict__ SBF,
    float* __restrict__ V, ushort* __restrict__ VBFA,
    const ushort* __restrict__ W1Tn, const float* __restrict__ b1n,
    const ushort* __restrict__ W2Tn, const float* __restrict__ b2n,
    ushort* __restrict__ PHIB)
{
    int tid = threadIdx.x;
    int w = tid >> 6, l = tid & 63;
    int bm = blockIdx.x * 16;
    int lrow = l & 15, lk = (l >> 4) * 8;
    __shared__ ushort sVVN[16][136];   // phase A: VVN; phase D: new-SBF tile
    __shared__ ushort Hs[16][136];

    // ---- phase A: u = v@U, vv = v@Vw for col-tiles {2w, 2w+1}; dot/uv stay in regs ----
    f32x4 au[3][2], av[3][2];
    #pragma unroll
    for (int c = 0; c < 3; c++)
        #pragma unroll
        for (int t = 0; t < 2; t++) {
            au[c][t] = (f32x4){0.f,0.f,0.f,0.f};
            av[c][t] = (f32x4){0.f,0.f,0.f,0.f};
        }
    #pragma unroll
    for (int k0 = 0; k0 < 128; k0 += 32) {
        bf16x8 af[3];
        #pragma unroll
        for (int c = 0; c < 3; c++)
            af[c] = *(const bf16x8*)&VBFB[(size_t)c*VPLANE + (size_t)(bm + lrow)*128 + k0 + lk];
        #pragma unroll
        for (int t = 0; t < 2; t++) {
            int nu = (2*w + t)*16 + lrow;
            bf16x8 bu = *(const bf16x8*)&UVT[(size_t)nu*128 + k0 + lk];
            bf16x8 bv = *(const bf16x8*)&UVT[(size_t)(nu + 128)*128 + k0 + lk];
            #pragma unroll
            for (int c = 0; c < 3; c++) {
                au[c][t] = __builtin_amdgcn_mfma_f32_16x16x32_bf16(af[c], bu, au[c][t], 0, 0, 0);
                av[c][t] = __builtin_amdgcn_mfma_f32_16x16x32_bf16(af[c], bv, av[c][t], 0, 0, 0);
            }
        }
    }
    float dotr[2][4], uvr[3][2][4];
    #pragma unroll
    for (int t = 0; t < 2; t++) {
        int k = (2*w + t)*16 + lrow;
        #pragma unroll
        for (int j = 0; j < 4; j++) {
            int row = (l >> 4)*4 + j;
            float u0 = au[0][t][j], u1 = au[1][t][j], u2 = au[2][t][j];
            float v0 = av[0][t][j], v1 = av[1][t][j], v2 = av[2][t][j];
            uvr[0][t][j] = u0; uvr[1][t][j] = u1; uvr[2][t][j] = u2;
            dotr[t][j] = u0*v0 + u1*v1 + u2*v2;
            sVVN[row][k] = f2bf(sqrtf(v0*v0 + v1*v1 + v2*v2 + EPSV));
        }
    }
    __syncthreads();

    // ---- phase B: h = silu([S|VVN]@a1 + b1) ----
    f32x4 acc[2] = {{0.f,0.f,0.f,0.f},{0.f,0.f,0.f,0.f}};
    #pragma unroll
    for (int k0 = 0; k0 < 256; k0 += 32) {
        bf16x8 af;
        if (k0 < 128) af = *(const bf16x8*)&SBF_in[(size_t)(bm + lrow)*128 + k0 + lk];
        else          af = *(const bf16x8*)&sVVN[lrow][k0 + lk - 128];
        #pragma unroll
        for (int t = 0; t < 2; t++) {
            int n = (2*w + t)*16 + lrow;
            bf16x8 bf = *(const bf16x8*)&A1T[(size_t)n*256 + k0 + lk];
            acc[t] = __builtin_amdgcn_mfma_f32_16x16x32_bf16(af, bf, acc[t], 0, 0, 0);
        }
    }
    #pragma unroll
    for (int t = 0; t < 2; t++) {
        int col = (2*w + t)*16 + lrow;
        float bv = a1b[col];
        #pragma unroll
        for (int j = 0; j < 4; j++) {
            int row = (l >> 4)*4 + j;
            float val = acc[t][j] + bv;
            val = val / (1.0f + __expf(-val));
            Hs[row][col] = f2bf(val);
        }
    }
    __syncthreads();

    // ---- phase C: a = h@a2 + b2; s/v update ----
    f32x4 c_vv[2], c_sv[2], c_ss[2];
    #pragma unroll
    for (int t = 0; t < 2; t++) {
        c_vv[t] = (f32x4){0.f,0.f,0.f,0.f};
        c_sv[t] = (f32x4){0.f,0.f,0.f,0.f};
        c_ss[t] = (f32x4){0.f,0.f,0.f,0.f};
    }
    #pragma unroll
    for (int k0 = 0; k0 < 128; k0 += 32) {
        bf16x8 af = *(const bf16x8*)&Hs[lrow][k0 + lk];
        #pragma unroll
        for (int t = 0; t < 2; t++) {
            int n0 = (2*w + t)*16 + lrow;
            bf16x8 b0 = *(const bf16x8*)&A2T[(size_t)n0*128 + k0 + lk];
            bf16x8 b1 = *(const bf16x8*)&A2T[(size_t)(n0 + 128)*128 + k0 + lk];
            bf16x8 b2 = *(const bf16x8*)&A2T[(size_t)(n0 + 256)*128 + k0 + lk];
            c_vv[t] = __builtin_amdgcn_mfma_f32_16x16x32_bf16(af, b0, c_vv[t], 0, 0, 0);
            c_sv[t] = __builtin_amdgcn_mfma_f32_16x16x32_bf16(af, b1, c_sv[t], 0, 0, 0);
            c_ss[t] = __builtin_amdgcn_mfma_f32_16x16x32_bf16(af, b2, c_ss[t], 0, 0, 0);
        }
    }
    #pragma unroll
    for (int t = 0; t < 2; t++) {
        int k = (2*w + t)*16 + lrow;
        float b_vv = a2b[k], b_sv = a2b[128 + k], b_ss = a2b[256 + k];
        #pragma unroll
        for (int j = 0; j < 4; j++) {
            int a = bm + (l >> 4)*4 + j;
            size_t base = (size_t)a*128 + k;
            float vv = c_vv[t][j] + b_vv;
            float sv = c_sv[t][j] + b_sv;
            float ss = c_ss[t][j] + b_ss;
            float sn = S[base] + ss + sv * dotr[t][j];
            S[base] = sn; SBF[base] = f2bf(sn);
            if (FUSE_MSG) sVVN[a - bm][k] = f2bf(sn);   // stage new S tile for phase D
            if (!LAST) {
                #pragma unroll
                for (int c = 0; c < 3; c++) {
                    size_t vb = (size_t)c*VPLANE + base;
                    float nv = V[vb] + vv * uvr[c][t][j];
                    V[vb] = nv; VBFA[vb] = f2bf(nv);
                }
            }
        }
    }

    // ---- phase D (FUSE_MSG): PHIB = (silu(Snew@w1n+b1n))@w2n+b2n for next layer ----
    if (FUSE_MSG) {
        __syncthreads();
        f32x4 accD[2] = {{0.f,0.f,0.f,0.f},{0.f,0.f,0.f,0.f}};
        #pragma unroll
        for (int k0 = 0; k0 < 128; k0 += 32) {
            bf16x8 af = *(const bf16x8*)&sVVN[lrow][k0 + lk];
            #pragma unroll
            for (int t = 0; t < 2; t++) {
                int n = (2*w + t)*16 + lrow;
                bf16x8 bf = *(const bf16x8*)&W1Tn[(size_t)n*128 + k0 + lk];
                accD[t] = __builtin_amdgcn_mfma_f32_16x16x32_bf16(af, bf, accD[t], 0, 0, 0);
            }
        }
        #pragma unroll
        for (int t = 0; t < 2; t++) {
            int col = (2*w + t)*16 + lrow;
            float bv = b1n[col];
            #pragma unroll
            for (int j = 0; j < 4; j++) {
                int row = (l >> 4)*4 + j;
                float val = accD[t][j] + bv;
                val = val / (1.0f + __expf(-val));
                Hs[row][col] = f2bf(val);
            }
        }
        __syncthreads();
        f32x4 accE[6];
        #pragma unroll
        for (int t = 0; t < 6; t++) accE[t] = (f32x4){0.f,0.f,0.f,0.f};
        #pragma unroll
        for (int k0 = 0; k0 < 128; k0 += 32) {
            bf16x8 af = *(const bf16x8*)&Hs[lrow][k0 + lk];
            #pragma unroll
            for (int t = 0; t < 6; t++) {
                int n = (6*w + t)*16 + lrow;
                bf16x8 bf = *(const bf16x8*)&W2Tn[(size_t)n*128 + k0 + lk];
                accE[t] = __builtin_amdgcn_mfma_f32_16x16x32_bf16(af, bf, accE[t], 0, 0, 0);
            }
        }
        #pragma unroll
        for (int t = 0; t < 6; t++) {
            int col = (6*w + t)*16 + lrow;
            float bv = b2n[col];
            #pragma unroll
            for (int j = 0; j < 4; j++) {
                int row = bm + (l >> 4)*4 + j;
                PHIB[(size_t)row*384 + col] = f2bf(accE[t][j] + bv);
            }
        }
    }
}

// ---------------- fused readout + molecule accumulation ----------------
__global__ __launch_bounds__(64) void k_readout(
    const ushort* __restrict__ SBF, const ushort* __restrict__ OW1T,
    const float* __restrict__ b1, const float* __restrict__ w2,
    const float* __restrict__ b2v, const int* __restrict__ mol,
    float* __restrict__ out)
{
    int l = threadIdx.x;
    int bm = blockIdx.x * 16;
    int lrow = l & 15, lk = (l >> 4) * 8;
    __shared__ float Hs[16][132];

    f32x4 acc[8];
    #pragma unroll
    for (int t = 0; t < 8; t++) acc[t] = (f32x4){0.f,0.f,0.f,0.f};
    #pragma unroll
    for (int k0 = 0; k0 < 128; k0 += 32) {
        bf16x8 af = *(const bf16x8*)&SBF[(size_t)(bm + lrow)*128 + k0 + lk];
        #pragma unroll
        for (int t = 0; t < 8; t++) {
            bf16x8 bf = *(const bf16x8*)&OW1T[(size_t)(t*16 + lrow)*128 + k0 + lk];
            acc[t] = __builtin_amdgcn_mfma_f32_16x16x32_bf16(af, bf, acc[t], 0, 0, 0);
        }
    }
    #pragma unroll
    for (int t = 0; t < 8; t++) {
        int col = t*16 + lrow;
        float bv = b1[col];
        #pragma unroll
        for (int j = 0; j < 4; j++) {
            int row = (l >> 4)*4 + j;
            float val = acc[t][j] + bv;
            Hs[row][col] = val / (1.0f + __expf(-val));
        }
    }
    __syncthreads();
    if (l < 16) {
        float s = b2v[0];
        #pragma unroll 8
        for (int k = 0; k < 128; k++) s += Hs[l][k] * w2[k];
        atomicAdd(&out[mol[bm + l]], s);
    }
}

extern "C" void kernel_launch(void* const* d_in, const int* in_sizes, int n_in,
                              void* d_out, int out_size, void* d_ws, size_t ws_size,
                              hipStream_t stream) {
    const int*   z      = (const int*)d_in[0];
    const float* pos    = (const float*)d_in[1];
    const int*   esrc   = (const int*)d_in[2];
    const int*   edst   = (const int*)d_in[3];
    const int*   mol    = (const int*)d_in[4];
    const float* embed  = (const float*)d_in[5];
    const float* msg_w1 = (const float*)d_in[6];
    const float* msg_b1 = (const float*)d_in[7];
    const float* msg_w2 = (const float*)d_in[8];
    const float* msg_b2 = (const float*)d_in[9];
    const float* rbf_w  = (const float*)d_in[10];
    const float* rbf_b  = (const float*)d_in[11];
    const float* upd_u  = (const float*)d_in[12];
    const float* upd_v  = (const float*)d_in[13];
    const float* upd_a1 = (const float*)d_in[14];
    const float* upd_a1b= (const float*)d_in[15];
    const float* upd_a2 = (const float*)d_in[16];
    const float* upd_a2b= (const float*)d_in[17];
    const float* out_w1 = (const float*)d_in[18];
    const float* out_b1 = (const float*)d_in[19];
    const float* out_w2 = (const float*)d_in[20];
    const float* out_b2 = (const float*)d_in[21];

    float* ws = (float*)d_ws;
    float* S      = ws; ws += 1048576;     // 8192*128 f32
    float* V      = ws; ws += 3145728;     // 3 planes [c][a][k]
    float* UNITFC = ws; ws += 1048576;     // sorted (ux,uy,uz,d)
    ushort* PHIB  = (ushort*)ws; ws += 1572864;   // 8192*384
    ushort* VBFA  = (ushort*)ws; ws += 1572864;   // v bf16 planes (gather)
    ushort* VBFB  = (ushort*)ws; ws += 1572864;   // post-agg v bf16 planes (GEMM A)
    ushort* SBF   = (ushort*)ws; ws += 524288;
    ushort* WT    = (ushort*)ws; ws += 278528;
    int* CNT  = (int*)ws;
    int* OFF  = CNT + 8192;
    int* CUR  = OFF + 8193;
    int* SRCS = CUR + 8192;

    hipMemsetAsync(CNT, 0, 8192 * sizeof(int), stream);
    hipMemsetAsync(d_out, 0, N_MOL * sizeof(float), stream);

    k_wconv<<<2176, 256, 0, stream>>>(msg_w1, msg_w2, upd_u, upd_v, upd_a1, upd_a2, out_w1, WT);
    k_embed<<<4096, 256, 0, stream>>>(z, embed, S, SBF);
    k_hist<<<1024, 256, 0, stream>>>(edst, CNT);
    k_scan<<<1, 1024, 0, stream>>>(CNT, OFF, CUR);
    k_edges<<<1024, 256, 0, stream>>>(pos, esrc, edst, CUR, UNITFC, SRCS);

    const ushort* W1T0 = WT;
    const ushort* W2T0 = WT + 49152;
    auto UVTl = [&](int l){ return WT + 196608 + l*32768; };
    auto A1Tl = [&](int l){ return WT + 294912 + l*32768; };
    auto A2Tl = [&](int l){ return WT + 393216 + l*49152; };
    auto W1Tl = [&](int l){ return WT + l*16384; };
    auto W2Tl = [&](int l){ return WT + 49152 + l*49152; };

    // layer 0
    k_msg<<<512, 256, 0, stream>>>(SBF, W1T0, msg_b1, W2T0, msg_b2, PHIB);
    k_aggregate<true><<<8192, 192, 0, stream>>>(PHIB, VBFA, S, SBF, V, VBFB,
        UNITFC, SRCS, OFF, rbf_w, rbf_b);
    k_upd<true,false><<<512, 256, 0, stream>>>(VBFB, UVTl(0), SBF, A1Tl(0), upd_a1b,
        A2Tl(0), upd_a2b, S, SBF, V, VBFA,
        W1Tl(1), msg_b1 + 128, W2Tl(1), msg_b2 + 384, PHIB);
    // layer 1
    k_aggregate<false><<<8192, 192, 0, stream>>>(PHIB, VBFA, S, SBF, V, VBFB,
        UNITFC, SRCS, OFF, rbf_w + (size_t)1*20*384, rbf_b + 384);
    k_upd<true,false><<<512, 256, 0, stream>>>(VBFB, UVTl(1), SBF, A1Tl(1), upd_a1b + 128,
        A2Tl(1), upd_a2b + 384, S, SBF, V, VBFA,
        W1Tl(2), msg_b1 + 256, W2Tl(2), msg_b2 + 768, PHIB);
    // layer 2
    k_aggregate<false><<<8192, 192, 0, stream>>>(PHIB, VBFA, S, SBF, V, VBFB,
        UNITFC, SRCS, OFF, rbf_w + (size_t)2*20*384, rbf_b + 768);
    k_upd<false,true><<<512, 256, 0, stream>>>(VBFB, UVTl(2), SBF, A1Tl(2), upd_a1b + 256,
        A2Tl(2), upd_a2b + 768, S, SBF, V, VBFA,
        nullptr, nullptr, nullptr, nullptr, nullptr);

    k_readout<<<512, 64, 0, stream>>>(SBF, WT + 540672, out_b1, out_w2, out_b2,
                                      mol, (float*)d_out);
}